// Round 1
// baseline (1599.864 us; speedup 1.0000x reference)
//
#include <hip/hip_runtime.h>
#include <math.h>

// Problem constants
// B=2, WAY=5, SHOT=5, K=5, Q=30, DIM=64, HW=441
// q rows: 60*64 = 3840 rows of 441 ; s rows: 50*64 = 3200 rows of 441
// ws layout (floats):
//   norm_all : [110*64][441]      = 3,104,640   (rows: 60 q-samples then 50 s-samples, [sample][d][h])
//   normT    : [110][441][64]     = 3,104,640
//   inv_norm : [7040]
//   pool     : [7040]             (row means of RAW input)
//   feats    : [2*30*15]          (only cols 0..4 used = cosine logits)
//   part_l   : [1200]             (per (e,q,w) x 4 d-quarters)
//   part_p   : [1200]             (per (e,q,w) x 4 h-quarters)
// total ~24.9 MB

#define HC 21

__global__ __launch_bounds__(256) void k1_rownorm(const float* __restrict__ in1,
                                                  const float* __restrict__ in2,
                                                  float* __restrict__ inv_norm,
                                                  float* __restrict__ pool) {
    int wv = threadIdx.x >> 6;
    int lane = threadIdx.x & 63;
    int rid = blockIdx.x * 4 + wv;  // 0..7039
    const float* src = (rid < 3840) ? (in1 + (size_t)rid * 441)
                                    : (in2 + (size_t)(rid - 3840) * 441);
    float s = 0.f, ss = 0.f;
#pragma unroll
    for (int i = 0; i < 7; ++i) {
        int h = lane + i * 64;
        if (h < 441) { float v = src[h]; s += v; ss = fmaf(v, v, ss); }
    }
#pragma unroll
    for (int off = 32; off > 0; off >>= 1) {
        s += __shfl_xor(s, off, 64);
        ss += __shfl_xor(ss, off, 64);
    }
    if (lane == 0) {
        inv_norm[rid] = 1.0f / sqrtf(ss);
        pool[rid] = s * (1.0f / 441.0f);
    }
}

__global__ __launch_bounds__(256) void k2_scale(const float* __restrict__ in1,
                                                const float* __restrict__ in2,
                                                const float* __restrict__ inv_norm,
                                                float* __restrict__ norm_all) {
    int idx = blockIdx.x * 256 + threadIdx.x;
    if (idx >= 110 * 64 * 441) return;
    int row = idx / 441;
    float v = (idx < 3840 * 441) ? in1[idx] : in2[idx - 3840 * 441];
    norm_all[idx] = v * inv_norm[row];
}

__global__ __launch_bounds__(256) void k3_transpose(const float* __restrict__ norm_all,
                                                    float* __restrict__ normT) {
    __shared__ float tile[64 * 63];
    int sample = blockIdx.x / 7;
    int ht = blockIdx.x % 7;
    int h0 = ht * 63;
    const float* src = norm_all + (size_t)sample * 64 * 441;
    for (int li = threadIdx.x; li < 64 * 63; li += 256) {
        int d = li / 63, hh = li % 63;
        tile[li] = src[d * 441 + h0 + hh];
    }
    __syncthreads();
    float* dst = normT + (size_t)sample * 441 * 64;
    for (int li = threadIdx.x; li < 63 * 64; li += 256) {
        int hh = li >> 6, d = li & 63;
        dst[(size_t)(h0 + hh) * 64 + d] = tile[d * 63 + hh];
    }
}

__global__ __launch_bounds__(256) void k4_cos(const float* __restrict__ pool,
                                              float* __restrict__ feats) {
    int e = blockIdx.x;
    __shared__ float qp[30 * 64], pr[5 * 64], qn[30], pn[5];
    int t = threadIdx.x;
    for (int li = t; li < 1920; li += 256) qp[li] = pool[e * 30 * 64 + li];
    for (int li = t; li < 320; li += 256) {
        int w = li >> 6, d = li & 63;
        float sm = 0.f;
        for (int sh = 0; sh < 5; ++sh) sm += pool[(60 + e * 25 + w * 5 + sh) * 64 + d];
        pr[li] = sm * 0.2f;
    }
    __syncthreads();
    if (t < 30) {
        float ss = 0.f;
        for (int d = 0; d < 64; ++d) { float v = qp[t * 64 + d]; ss = fmaf(v, v, ss); }
        qn[t] = 1.0f / sqrtf(ss);
    }
    if (t >= 32 && t < 37) {
        int w = t - 32; float ss = 0.f;
        for (int d = 0; d < 64; ++d) { float v = pr[w * 64 + d]; ss = fmaf(v, v, ss); }
        pn[w] = 1.0f / sqrtf(ss);
    }
    __syncthreads();
    if (t < 150) {
        int q = t / 5, w = t % 5;
        float dp = 0.f;
        for (int d = 0; d < 64; ++d) dp = fmaf(qp[q * 64 + d], pr[w * 64 + d], dp);
        feats[(e * 30 + q) * 15 + w] = dp * qn[q] * pn[w];
    }
}

// sim_l: block = (e,q,w,d-quarter). C[16][320] = sum_h Q[d][h]*S[k][h], top5 per d over k, sum.
__global__ __launch_bounds__(256) void k5_siml(const float* __restrict__ norm_all,
                                               float* __restrict__ part_l) {
    __shared__ float sbuf[16 * HC + 320 * HC];  // Q tile then S tile (7056 floats)
    __shared__ float dred[16];
    int bid = blockIdx.x;
    int dq = bid & 3; int r = bid >> 2;
    int w = r % 5; r /= 5;
    int q = r % 30; int e = r / 30;
    int t = threadIdx.x;
    int kg = t & 63, dg = t >> 6;

    const int qrowbase = (e * 30 + q) * 64 + dq * 16;
    const int srowbase = (60 + e * 25 + w * 5) * 64;  // 320 contiguous rows

    float acc[4][5];
#pragma unroll
    for (int i = 0; i < 4; ++i)
#pragma unroll
        for (int j = 0; j < 5; ++j) acc[i][j] = 0.f;

    float* Qs = sbuf;
    float* Ss = sbuf + 16 * HC;

    for (int c = 0; c < 21; ++c) {
        int h0 = c * HC;
        __syncthreads();
        for (int li = t; li < 16 * HC; li += 256) {
            int dd = li / HC, hh = li % HC;
            Qs[li] = norm_all[(size_t)(qrowbase + dd) * 441 + h0 + hh];
        }
        for (int li = t; li < 320 * HC; li += 256) {
            int kk = li / HC, hh = li % HC;
            Ss[li] = norm_all[(size_t)(srowbase + kk) * 441 + h0 + hh];
        }
        __syncthreads();
        for (int hh = 0; hh < HC; ++hh) {
            float q0 = Qs[(dg * 4 + 0) * HC + hh];
            float q1 = Qs[(dg * 4 + 1) * HC + hh];
            float q2 = Qs[(dg * 4 + 2) * HC + hh];
            float q3 = Qs[(dg * 4 + 3) * HC + hh];
#pragma unroll
            for (int j = 0; j < 5; ++j) {
                float sv = Ss[(kg * 5 + j) * HC + hh];
                acc[0][j] = fmaf(q0, sv, acc[0][j]);
                acc[1][j] = fmaf(q1, sv, acc[1][j]);
                acc[2][j] = fmaf(q2, sv, acc[2][j]);
                acc[3][j] = fmaf(q3, sv, acc[3][j]);
            }
        }
    }
    __syncthreads();
    // dump C[16][320]
#pragma unroll
    for (int i = 0; i < 4; ++i)
#pragma unroll
        for (int j = 0; j < 5; ++j)
            sbuf[(dg * 4 + i) * 320 + kg * 5 + j] = acc[i][j];
    __syncthreads();
    if (t < 16) {
        float m0 = -1e30f, m1 = -1e30f, m2 = -1e30f, m3 = -1e30f, m4 = -1e30f;
        const float* row = sbuf + t * 320;
        for (int k = 0; k < 320; ++k) {
            float v = row[k];
            if (v > m4) {
                if (v > m2) {
                    if (v > m1) {
                        if (v > m0) { m4 = m3; m3 = m2; m2 = m1; m1 = m0; m0 = v; }
                        else        { m4 = m3; m3 = m2; m2 = m1; m1 = v; }
                    } else { m4 = m3; m3 = m2; m2 = v; }
                } else {
                    if (v > m3) { m4 = m3; m3 = v; } else m4 = v;
                }
            }
        }
        dred[t] = m0 + m1 + m2 + m3 + m4;
    }
    __syncthreads();
    if (t == 0) {
        float sm = 0.f;
#pragma unroll
        for (int i = 0; i < 16; ++i) sm += dred[i];
        part_l[bid] = sm;
    }
}

// sim_p: block = (e,q,w,h-quarter). thread = one (q,h) row; q-vec in regs; stream s-cols from LDS.
__global__ __launch_bounds__(128) void k6_simp(const float* __restrict__ normT,
                                               float* __restrict__ part_p) {
    __shared__ float Ss[63 * 64];
    __shared__ float red[128];
    int bid = blockIdx.x;
    int qtr = bid & 3; int r = bid >> 2;
    int w = r % 5; r /= 5;
    int q = r % 30; int e = r / 30;
    int t = threadIdx.x;

    int hstart = (qtr * 441) >> 2;        // 0,110,220,330
    int hend = ((qtr + 1) * 441) >> 2;    // 110,220,330,441
    int cnt = hend - hstart;
    int h = hstart + (t < cnt ? t : cnt - 1);
    bool active = (t < cnt);

    float4 qv[16];
    const float4* qp = (const float4*)(normT + ((size_t)(e * 30 + q) * 441 + h) * 64);
#pragma unroll
    for (int i = 0; i < 16; ++i) qv[i] = qp[i];

    float m0 = -1e30f, m1 = -1e30f, m2 = -1e30f, m3 = -1e30f, m4 = -1e30f;

    for (int sh = 0; sh < 5; ++sh) {
        const float* sbase = normT + (size_t)(60 + e * 25 + w * 5 + sh) * 441 * 64;
        for (int c = 0; c < 7; ++c) {
            __syncthreads();
            const float4* src = (const float4*)(sbase + (size_t)c * 63 * 64);
            float4* dst4 = (float4*)Ss;
            for (int li = t; li < 63 * 16; li += 128) dst4[li] = src[li];
            __syncthreads();
#pragma unroll 2
            for (int kk = 0; kk < 63; ++kk) {
                const float4* sp = (const float4*)(Ss + kk * 64);
                float p0 = 0.f, p1 = 0.f, p2 = 0.f, p3 = 0.f;
#pragma unroll
                for (int i = 0; i < 16; i += 4) {
                    float4 s0 = sp[i + 0], s1 = sp[i + 1], s2 = sp[i + 2], s3 = sp[i + 3];
                    p0 = fmaf(qv[i + 0].x, s0.x, p0); p0 = fmaf(qv[i + 0].y, s0.y, p0);
                    p0 = fmaf(qv[i + 0].z, s0.z, p0); p0 = fmaf(qv[i + 0].w, s0.w, p0);
                    p1 = fmaf(qv[i + 1].x, s1.x, p1); p1 = fmaf(qv[i + 1].y, s1.y, p1);
                    p1 = fmaf(qv[i + 1].z, s1.z, p1); p1 = fmaf(qv[i + 1].w, s1.w, p1);
                    p2 = fmaf(qv[i + 2].x, s2.x, p2); p2 = fmaf(qv[i + 2].y, s2.y, p2);
                    p2 = fmaf(qv[i + 2].z, s2.z, p2); p2 = fmaf(qv[i + 2].w, s2.w, p2);
                    p3 = fmaf(qv[i + 3].x, s3.x, p3); p3 = fmaf(qv[i + 3].y, s3.y, p3);
                    p3 = fmaf(qv[i + 3].z, s3.z, p3); p3 = fmaf(qv[i + 3].w, s3.w, p3);
                }
                float v = (p0 + p1) + (p2 + p3);
                if (v > m4) {
                    if (v > m2) {
                        if (v > m1) {
                            if (v > m0) { m4 = m3; m3 = m2; m2 = m1; m1 = m0; m0 = v; }
                            else        { m4 = m3; m3 = m2; m2 = m1; m1 = v; }
                        } else { m4 = m3; m3 = m2; m2 = v; }
                    } else {
                        if (v > m3) { m4 = m3; m3 = v; } else m4 = v;
                    }
                }
            }
        }
    }
    red[t] = active ? (m0 + m1 + m2 + m3 + m4) : 0.f;
    __syncthreads();
#pragma unroll
    for (int s2 = 64; s2 > 0; s2 >>= 1) {
        if (t < s2) red[t] += red[t + s2];
        __syncthreads();
    }
    if (t == 0) part_p[bid] = red[0];
}

__global__ __launch_bounds__(256) void k7_final(const float* __restrict__ feats,
                                                const float* __restrict__ part_l,
                                                const float* __restrict__ part_p,
                                                const float* __restrict__ gamma,
                                                const float* __restrict__ beta,
                                                const float* __restrict__ convw,
                                                float* __restrict__ out) {
    int e = blockIdx.x;
    __shared__ float f[30 * 15], mu[15], inv[15];
    int t = threadIdx.x;
    if (t < 150) {
        int q = t / 5, w = t % 5;
        int pb = ((e * 30 + q) * 5 + w) * 4;
        f[q * 15 + w] = feats[(e * 30 + q) * 15 + w];
        f[q * 15 + 5 + w] = part_l[pb] + part_l[pb + 1] + part_l[pb + 2] + part_l[pb + 3];
        f[q * 15 + 10 + w] = part_p[pb] + part_p[pb + 1] + part_p[pb + 2] + part_p[pb + 3];
    }
    __syncthreads();
    if (t < 15) {
        float s1 = 0.f;
        for (int q = 0; q < 30; ++q) s1 += f[q * 15 + t];
        float m = s1 * (1.0f / 30.0f);
        float s2 = 0.f;
        for (int q = 0; q < 30; ++q) { float d = f[q * 15 + t] - m; s2 = fmaf(d, d, s2); }
        mu[t] = m;
        inv[t] = 1.0f / sqrtf(s2 * (1.0f / 30.0f) + 1e-5f);
    }
    __syncthreads();
    if (t < 150) {
        int q = t / 5, j = t % 5;
        float w0 = convw[0], w1 = convw[1], w2 = convw[2];
        float b0 = (f[q * 15 + j]      - mu[j])      * inv[j]      * gamma[j]      + beta[j];
        float b1 = (f[q * 15 + 5 + j]  - mu[5 + j])  * inv[5 + j]  * gamma[5 + j]  + beta[5 + j];
        float b2 = (f[q * 15 + 10 + j] - mu[10 + j]) * inv[10 + j] * gamma[10 + j] + beta[10 + j];
        out[e * 150 + q * 5 + j] = w0 * b0 + w1 * b1 + w2 * b2;
    }
}

extern "C" void kernel_launch(void* const* d_in, const int* in_sizes, int n_in,
                              void* d_out, int out_size, void* d_ws, size_t ws_size,
                              hipStream_t stream) {
    const float* in1 = (const float*)d_in[0];
    const float* in2 = (const float*)d_in[1];
    const float* gamma = (const float*)d_in[2];
    const float* beta = (const float*)d_in[3];
    const float* convw = (const float*)d_in[4];
    float* out = (float*)d_out;

    float* ws = (float*)d_ws;
    float* norm_all = ws;                     // 3,104,640
    float* normT    = ws + 3104640;           // 3,104,640
    float* inv_norm = ws + 6209280;           // 7040
    float* pool     = inv_norm + 7040;        // 7040
    float* feats    = pool + 7040;            // 900
    float* part_l   = feats + 900;            // 1200
    float* part_p   = part_l + 1200;          // 1200

    k1_rownorm<<<dim3(1760), dim3(256), 0, stream>>>(in1, in2, inv_norm, pool);
    k2_scale<<<dim3(12128), dim3(256), 0, stream>>>(in1, in2, inv_norm, norm_all);
    k3_transpose<<<dim3(770), dim3(256), 0, stream>>>(norm_all, normT);
    k4_cos<<<dim3(2), dim3(256), 0, stream>>>(pool, feats);
    k5_siml<<<dim3(1200), dim3(256), 0, stream>>>(norm_all, part_l);
    k6_simp<<<dim3(1200), dim3(128), 0, stream>>>(normT, part_p);
    k7_final<<<dim3(2), dim3(256), 0, stream>>>(feats, part_l, part_p, gamma, beta, convw, out);
}

// Round 2
// 332.614 us; speedup vs baseline: 4.8100x; 4.8100x over previous
//
#include <hip/hip_runtime.h>
#include <math.h>

// B=2, WAY=5, SHOT=5, K=5, Q=30, DIM=64, HW=441
// MFMA plan (16x16x32 bf16, 3-term split bf16 = fp32-ish accuracy):
//  ip_p (pixel): per (e,w): C^T[k=sh*441+h (2205->2208)][col=(q,h) packed per-q 448] , K=d(64)
//  ip_l (chan) : per (e,w): C^T[k=sh*64+d' (320)][col=(q,d) 1920], K=h(441->448)
// Transposed output => each lane's C column = one query row => per-lane top5 regs.

typedef __attribute__((ext_vector_type(8))) short bf16x8;
typedef __attribute__((ext_vector_type(4))) float f32x4;

#define MFMA16(a, b, c) __builtin_amdgcn_mfma_f32_16x16x32_bf16((a), (b), (c), 0, 0, 0)

__device__ __forceinline__ void split_bf16(float v, unsigned short& hi, unsigned short& lo) {
    unsigned int u = __float_as_uint(v);
    unsigned int r = u + 0x7FFFu + ((u >> 16) & 1u);
    hi = (unsigned short)(r >> 16);
    float hf = __uint_as_float(((unsigned int)hi) << 16);
    float l = v - hf;
    unsigned int u2 = __float_as_uint(l);
    unsigned int r2 = u2 + 0x7FFFu + ((u2 >> 16) & 1u);
    lo = (unsigned short)(r2 >> 16);
}

// sorted-desc top5 insert: m[0] >= m[1] >= ... >= m[4]
__device__ __forceinline__ void ins5(float m[5], float v) {
    m[4] = fminf(fmaxf(v, m[4]), m[3]);   // med3(v, m3, m4)
    m[3] = fminf(fmaxf(v, m[3]), m[2]);
    m[2] = fminf(fmaxf(v, m[2]), m[1]);
    m[1] = fminf(fmaxf(v, m[1]), m[0]);
    m[0] = fmaxf(m[0], v);
}

// ---------------- k1: row norms (1/||row||) + row means of raw input ----------------
__global__ __launch_bounds__(256) void k1_rownorm(const float* __restrict__ in1,
                                                  const float* __restrict__ in2,
                                                  float* __restrict__ inv_norm,
                                                  float* __restrict__ pool) {
    int wv = threadIdx.x >> 6;
    int lane = threadIdx.x & 63;
    int rid = blockIdx.x * 4 + wv;  // 0..7039
    const float* src = (rid < 3840) ? (in1 + (size_t)rid * 441)
                                    : (in2 + (size_t)(rid - 3840) * 441);
    float s = 0.f, ss = 0.f;
#pragma unroll
    for (int i = 0; i < 7; ++i) {
        int h = lane + i * 64;
        if (h < 441) { float v = src[h]; s += v; ss = fmaf(v, v, ss); }
    }
#pragma unroll
    for (int off = 32; off > 0; off >>= 1) {
        s += __shfl_xor(s, off, 64);
        ss += __shfl_xor(ss, off, 64);
    }
    if (lane == 0) {
        inv_norm[rid] = 1.0f / sqrtf(ss);
        pool[rid] = s * (1.0f / 441.0f);
    }
}

// ---------------- k4: cosine logits ----------------
__global__ __launch_bounds__(256) void k4_cos(const float* __restrict__ pool,
                                              float* __restrict__ feats) {
    int e = blockIdx.x;
    __shared__ float qp[30 * 64], pr[5 * 64], qn[30], pn[5];
    int t = threadIdx.x;
    for (int li = t; li < 1920; li += 256) qp[li] = pool[e * 30 * 64 + li];
    for (int li = t; li < 320; li += 256) {
        int w = li >> 6, d = li & 63;
        float sm = 0.f;
        for (int sh = 0; sh < 5; ++sh) sm += pool[(60 + e * 25 + w * 5 + sh) * 64 + d];
        pr[li] = sm * 0.2f;
    }
    __syncthreads();
    if (t < 30) {
        float ss = 0.f;
        for (int d = 0; d < 64; ++d) { float v = qp[t * 64 + d]; ss = fmaf(v, v, ss); }
        qn[t] = 1.0f / sqrtf(ss);
    }
    if (t >= 32 && t < 37) {
        int w = t - 32; float ss = 0.f;
        for (int d = 0; d < 64; ++d) { float v = pr[w * 64 + d]; ss = fmaf(v, v, ss); }
        pn[w] = 1.0f / sqrtf(ss);
    }
    __syncthreads();
    if (t < 150) {
        int q = t / 5, w = t % 5;
        float dp = 0.f;
        for (int d = 0; d < 64; ++d) dp = fmaf(qp[q * 64 + d], pr[w * 64 + d], dp);
        feats[(e * 30 + q) * 15 + w] = dp * qn[q] * pn[w];
    }
}

// ---------------- pack kernels: build split-bf16 MFMA fragments ----------------
// Frag convention (16x16x32): row/col = lane&15 ; k = (lane>>4)*8 + j (j = 0..7 consecutive)

// Pq: B-side of ip_p. [e][gcs=q*28+cs][ks(2)][lane] x8bf16 ; col=h=cs*16+(lane&15), k=d
__global__ __launch_bounds__(256) void pack_q6(const float* __restrict__ in1,
                                               const float* __restrict__ inv_norm,
                                               uint4* __restrict__ Pq_hi, uint4* __restrict__ Pq_lo) {
    int idx = blockIdx.x * 256 + threadIdx.x;   // 215040
    int lane = idx & 63;
    int ks = (idx >> 6) & 1;
    int rest = idx >> 7;
    int gcs = rest % 840, e = rest / 840;
    int q = gcs / 28, cs = gcs % 28;
    int h = cs * 16 + (lane & 15);
    int d0 = ks * 32 + ((lane >> 4) << 3);
    int rowq = (e * 30 + q) * 64;
    unsigned short hs[8], ls[8];
#pragma unroll
    for (int j = 0; j < 8; ++j) {
        int d = d0 + j;
        float v = (h < 441) ? in1[(size_t)(rowq + d) * 441 + h] * inv_norm[rowq + d] : 0.f;
        split_bf16(v, hs[j], ls[j]);
    }
    uint4 H, L;
    H.x = hs[0] | (hs[1] << 16); H.y = hs[2] | (hs[3] << 16);
    H.z = hs[4] | (hs[5] << 16); H.w = hs[6] | (hs[7] << 16);
    L.x = ls[0] | (ls[1] << 16); L.y = ls[2] | (ls[3] << 16);
    L.z = ls[4] | (ls[5] << 16); L.w = ls[6] | (ls[7] << 16);
    Pq_hi[idx] = H; Pq_lo[idx] = L;
}

// Ps: A-side of ip_p. [ew][kt(138)][ks(2)][lane] ; row=kidx=kt*16+(lane&15), k=d
__global__ __launch_bounds__(256) void pack_s6(const float* __restrict__ in2,
                                               const float* __restrict__ inv_norm,
                                               uint4* __restrict__ Ps_hi, uint4* __restrict__ Ps_lo) {
    int idx = blockIdx.x * 256 + threadIdx.x;   // 176640
    int lane = idx & 63;
    int ks = (idx >> 6) & 1;
    int rest = idx >> 7;
    int kt = rest % 138, ew = rest / 138;
    int kidx = kt * 16 + (lane & 15);
    bool valid = kidx < 2205;
    int kc = valid ? kidx : 0;
    int sh = kc / 441;
    int h = kc - sh * 441;
    int e = ew / 5, w = ew % 5;
    int srow = ((e * 25 + w * 5 + sh) * 64);   // in2 row-base; inv_norm offset 3840
    int d0 = ks * 32 + ((lane >> 4) << 3);
    unsigned short hs[8], ls[8];
#pragma unroll
    for (int j = 0; j < 8; ++j) {
        int d = d0 + j;
        float v = valid ? in2[(size_t)(srow + d) * 441 + h] * inv_norm[3840 + srow + d] : 0.f;
        split_bf16(v, hs[j], ls[j]);
    }
    uint4 H, L;
    H.x = hs[0] | (hs[1] << 16); H.y = hs[2] | (hs[3] << 16);
    H.z = hs[4] | (hs[5] << 16); H.w = hs[6] | (hs[7] << 16);
    L.x = ls[0] | (ls[1] << 16); L.y = ls[2] | (ls[3] << 16);
    L.z = ls[4] | (ls[5] << 16); L.w = ls[6] | (ls[7] << 16);
    Ps_hi[idx] = H; Ps_lo[idx] = L;
}

// Al: A-side of ip_l. [ew][rt(20)][ks(14)][lane] ; row=sh*64+d'=rt*16+(lane&15), k=h
__global__ __launch_bounds__(256) void pack_lA(const float* __restrict__ in2,
                                               const float* __restrict__ inv_norm,
                                               uint4* __restrict__ Al_hi, uint4* __restrict__ Al_lo) {
    int idx = blockIdx.x * 256 + threadIdx.x;   // 179200
    int lane = idx & 63;
    int t2 = idx >> 6;
    int ks = t2 % 14;
    int t3 = t2 / 14;
    int rt = t3 % 20, ew = t3 / 20;
    int e = ew / 5, w = ew % 5;
    int row = rt * 16 + (lane & 15);            // < 320
    int sh = row >> 6, dp = row & 63;
    int srow = (e * 25 + w * 5 + sh) * 64 + dp;
    int h0 = ks * 32 + ((lane >> 4) << 3);
    const float* src = in2 + (size_t)srow * 441;
    float inv = inv_norm[3840 + srow];
    unsigned short hs[8], ls[8];
#pragma unroll
    for (int j = 0; j < 8; ++j) {
        int h = h0 + j;
        float v = (h < 441) ? src[h] * inv : 0.f;
        split_bf16(v, hs[j], ls[j]);
    }
    uint4 H, L;
    H.x = hs[0] | (hs[1] << 16); H.y = hs[2] | (hs[3] << 16);
    H.z = hs[4] | (hs[5] << 16); H.w = hs[6] | (hs[7] << 16);
    L.x = ls[0] | (ls[1] << 16); L.y = ls[2] | (ls[3] << 16);
    L.z = ls[4] | (ls[5] << 16); L.w = ls[6] | (ls[7] << 16);
    Al_hi[idx] = H; Al_lo[idx] = L;
}

// Bl: B-side of ip_l. [e][gct(120)][ks(14)][lane] ; col=q*64+d=gct*16+(lane&15), k=h
__global__ __launch_bounds__(256) void pack_lB(const float* __restrict__ in1,
                                               const float* __restrict__ inv_norm,
                                               uint4* __restrict__ Bl_hi, uint4* __restrict__ Bl_lo) {
    int idx = blockIdx.x * 256 + threadIdx.x;   // 215040
    int lane = idx & 63;
    int t2 = idx >> 6;
    int ks = t2 % 14;
    int t3 = t2 / 14;
    int gct = t3 % 120, e = t3 / 120;
    int col = gct * 16 + (lane & 15);
    int q = col >> 6, d = col & 63;
    int qrow = (e * 30 + q) * 64 + d;
    int h0 = ks * 32 + ((lane >> 4) << 3);
    const float* src = in1 + (size_t)qrow * 441;
    float inv = inv_norm[qrow];
    unsigned short hs[8], ls[8];
#pragma unroll
    for (int j = 0; j < 8; ++j) {
        int h = h0 + j;
        float v = (h < 441) ? src[h] * inv : 0.f;
        split_bf16(v, hs[j], ls[j]);
    }
    uint4 H, L;
    H.x = hs[0] | (hs[1] << 16); H.y = hs[2] | (hs[3] << 16);
    H.z = hs[4] | (hs[5] << 16); H.w = hs[6] | (hs[7] << 16);
    L.x = ls[0] | (ls[1] << 16); L.y = ls[2] | (ls[3] << 16);
    L.z = ls[4] | (ls[5] << 16); L.w = ls[6] | (ls[7] << 16);
    Bl_hi[idx] = H; Bl_lo[idx] = L;
}

// ---------------- k6: pixel similarity via MFMA ----------------
// 1 wave / block. Wave owns 4 col-tiles (64 h-cols of one q), sweeps all 138 k-tiles.
__global__ __launch_bounds__(64) void k6_mfma(const bf16x8* __restrict__ Pq_hi,
                                              const bf16x8* __restrict__ Pq_lo,
                                              const bf16x8* __restrict__ Ps_hi,
                                              const bf16x8* __restrict__ Ps_lo,
                                              float* __restrict__ part_p) {
    int gw = blockIdx.x;              // 2100 = 2e*5w*210
    int gwave = gw % 210;
    int r = gw / 210;
    int w = r % 5, e = r / 5;
    int lane = threadIdx.x;
    int gcs0 = gwave * 4;
    int q = gwave / 7;                // = gcs0/28
    int ew = e * 5 + w;

    bf16x8 Bh[4][2], Bl[4][2];
#pragma unroll
    for (int s = 0; s < 4; ++s)
#pragma unroll
        for (int ks = 0; ks < 2; ++ks) {
            int gi = ((e * 840 + gcs0 + s) * 2 + ks) * 64 + lane;
            Bh[s][ks] = Pq_hi[gi];
            Bl[s][ks] = Pq_lo[gi];
        }

    float m[4][5];
#pragma unroll
    for (int s = 0; s < 4; ++s)
#pragma unroll
        for (int i = 0; i < 5; ++i) m[s][i] = -1e30f;

    int rowbase = (lane >> 4) * 4;

    int abase = (ew * 138) * 2 * 64 + lane;
    bf16x8 Ah0 = Ps_hi[abase], Ah1 = Ps_hi[abase + 64];
    bf16x8 Al0 = Ps_lo[abase], Al1 = Ps_lo[abase + 64];

    for (int kt = 0; kt < 138; ++kt) {
        bf16x8 nAh0, nAh1, nAl0, nAl1;
        if (kt < 137) {
            int nb = abase + (kt + 1) * 128;
            nAh0 = Ps_hi[nb]; nAh1 = Ps_hi[nb + 64];
            nAl0 = Ps_lo[nb]; nAl1 = Ps_lo[nb + 64];
        }
#pragma unroll
        for (int s = 0; s < 4; ++s) {
            f32x4 c = {0.f, 0.f, 0.f, 0.f};
            c = MFMA16(Ah0, Bh[s][0], c);
            c = MFMA16(Ah1, Bh[s][1], c);
            c = MFMA16(Ah0, Bl[s][0], c);
            c = MFMA16(Ah1, Bl[s][1], c);
            c = MFMA16(Al0, Bh[s][0], c);
            c = MFMA16(Al1, Bh[s][1], c);
            if (kt == 137) {
#pragma unroll
                for (int reg = 0; reg < 4; ++reg) {
                    float v = (rowbase + reg < 13) ? c[reg] : -1e30f;
                    ins5(m[s], v);
                }
            } else {
#pragma unroll
                for (int reg = 0; reg < 4; ++reg) ins5(m[s], c[reg]);
            }
        }
        Ah0 = nAh0; Ah1 = nAh1; Al0 = nAl0; Al1 = nAl1;
    }

    // merge per-set top5 across the 4 lane-groups (row quads)
#pragma unroll
    for (int mask = 16; mask <= 32; mask <<= 1) {
        float ov[4][5];
#pragma unroll
        for (int s = 0; s < 4; ++s)
#pragma unroll
            for (int i = 0; i < 5; ++i) ov[s][i] = __shfl_xor(m[s][i], mask, 64);
#pragma unroll
        for (int s = 0; s < 4; ++s)
#pragma unroll
            for (int i = 0; i < 5; ++i) ins5(m[s], ov[s][i]);
    }

    float tot = 0.f;
#pragma unroll
    for (int s = 0; s < 4; ++s) {
        float s5 = m[s][0] + m[s][1] + m[s][2] + m[s][3] + m[s][4];
        int h = ((gcs0 + s) % 28) * 16 + (lane & 15);
        s5 = (h < 441) ? s5 : 0.f;
#pragma unroll
        for (int mask = 1; mask <= 8; mask <<= 1) s5 += __shfl_xor(s5, mask, 64);
        tot += s5;
    }
    if (lane == 0) {
        int slot = gwave - 7 * q;     // 0..6
        part_p[((e * 30 + q) * 5 + w) * 7 + slot] = tot;
    }
}

// ---------------- k5: channel similarity via MFMA ----------------
// block = (e,q,w), 4 waves; Bh (q-side, full K) staged in LDS; wave does 5 row-tiles.
__global__ __launch_bounds__(256) void k5_mfma(const bf16x8* __restrict__ Bl_hi,
                                               const bf16x8* __restrict__ Bl_lo,
                                               const bf16x8* __restrict__ Al_hi,
                                               const bf16x8* __restrict__ Al_lo,
                                               float* __restrict__ siml) {
    __shared__ bf16x8 BH[14 * 4 * 64];     // 57344 B
    __shared__ float M[4][64][5];          // 5120 B
    int b = blockIdx.x;                    // 300
    int w = b % 5;
    int r = b / 5;
    int q = r % 30, e = r / 30;
    int t = threadIdx.x;
    int lane = t & 63, wid = t >> 6;
    int ew = e * 5 + w;

    for (int i = t; i < 3584; i += 256) {
        int ks = i >> 8;
        int rem = i & 255;
        int set = rem >> 6, ln = rem & 63;
        BH[i] = Bl_hi[((e * 120 + q * 4 + set) * 14 + ks) * 64 + ln];
    }
    __syncthreads();

    float m[4][5];
#pragma unroll
    for (int s = 0; s < 4; ++s)
#pragma unroll
        for (int i = 0; i < 5; ++i) m[s][i] = -1e30f;

    for (int rr = 0; rr < 5; ++rr) {
        int rt = wid * 5 + rr;
        f32x4 c[4];
#pragma unroll
        for (int s = 0; s < 4; ++s) c[s] = (f32x4){0.f, 0.f, 0.f, 0.f};
        for (int ks = 0; ks < 14; ++ks) {
            int ga = ((ew * 20 + rt) * 14 + ks) * 64 + lane;
            bf16x8 Ah = Al_hi[ga], Alo = Al_lo[ga];
#pragma unroll
            for (int s = 0; s < 4; ++s) {
                bf16x8 bh = BH[(ks * 4 + s) * 64 + lane];
                bf16x8 bl = Bl_lo[((e * 120 + q * 4 + s) * 14 + ks) * 64 + lane];
                c[s] = MFMA16(Ah, bh, c[s]);
                c[s] = MFMA16(Ah, bl, c[s]);
                c[s] = MFMA16(Alo, bh, c[s]);
            }
        }
#pragma unroll
        for (int s = 0; s < 4; ++s)
#pragma unroll
            for (int reg = 0; reg < 4; ++reg) ins5(m[s], c[s][reg]);
    }

#pragma unroll
    for (int mask = 16; mask <= 32; mask <<= 1) {
        float ov[4][5];
#pragma unroll
        for (int s = 0; s < 4; ++s)
#pragma unroll
            for (int i = 0; i < 5; ++i) ov[s][i] = __shfl_xor(m[s][i], mask, 64);
#pragma unroll
        for (int s = 0; s < 4; ++s)
#pragma unroll
            for (int i = 0; i < 5; ++i) ins5(m[s], ov[s][i]);
    }

    if (lane < 16) {
#pragma unroll
        for (int s = 0; s < 4; ++s)
#pragma unroll
            for (int i = 0; i < 5; ++i) M[wid][s * 16 + lane][i] = m[s][i];
    }
    __syncthreads();

    if (t < 64) {
        float lst[5];
#pragma unroll
        for (int i = 0; i < 5; ++i) lst[i] = M[0][t][i];
#pragma unroll
        for (int wv = 1; wv < 4; ++wv)
#pragma unroll
            for (int i = 0; i < 5; ++i) ins5(lst, M[wv][t][i]);
        float s5 = lst[0] + lst[1] + lst[2] + lst[3] + lst[4];
#pragma unroll
        for (int mask = 1; mask <= 32; mask <<= 1) s5 += __shfl_xor(s5, mask, 64);
        if (t == 0) siml[(e * 30 + q) * 5 + w] = s5;
    }
}

// ---------------- k7: BN (episode stats) + dilated conv ----------------
__global__ __launch_bounds__(256) void k7_final(const float* __restrict__ feats,
                                                const float* __restrict__ siml,
                                                const float* __restrict__ part_p,
                                                const float* __restrict__ gamma,
                                                const float* __restrict__ beta,
                                                const float* __restrict__ convw,
                                                float* __restrict__ out) {
    int e = blockIdx.x;
    __shared__ float f[30 * 15], mu[15], inv[15];
    int t = threadIdx.x;
    if (t < 150) {
        int q = t / 5, w = t % 5;
        int pb = ((e * 30 + q) * 5 + w) * 7;
        float sp = 0.f;
#pragma unroll
        for (int s = 0; s < 7; ++s) sp += part_p[pb + s];
        f[q * 15 + w] = feats[(e * 30 + q) * 15 + w];
        f[q * 15 + 5 + w] = siml[(e * 30 + q) * 5 + w];
        f[q * 15 + 10 + w] = sp;
    }
    __syncthreads();
    if (t < 15) {
        float s1 = 0.f;
        for (int q = 0; q < 30; ++q) s1 += f[q * 15 + t];
        float mn = s1 * (1.0f / 30.0f);
        float s2 = 0.f;
        for (int q = 0; q < 30; ++q) { float d = f[q * 15 + t] - mn; s2 = fmaf(d, d, s2); }
        mu[t] = mn;
        inv[t] = 1.0f / sqrtf(s2 * (1.0f / 30.0f) + 1e-5f);
    }
    __syncthreads();
    if (t < 150) {
        int q = t / 5, j = t % 5;
        float w0 = convw[0], w1 = convw[1], w2 = convw[2];
        float b0 = (f[q * 15 + j]      - mu[j])      * inv[j]      * gamma[j]      + beta[j];
        float b1 = (f[q * 15 + 5 + j]  - mu[5 + j])  * inv[5 + j]  * gamma[5 + j]  + beta[5 + j];
        float b2 = (f[q * 15 + 10 + j] - mu[10 + j]) * inv[10 + j] * gamma[10 + j] + beta[10 + j];
        out[e * 150 + q * 5 + j] = w0 * b0 + w1 * b1 + w2 * b2;
    }
}

extern "C" void kernel_launch(void* const* d_in, const int* in_sizes, int n_in,
                              void* d_out, int out_size, void* d_ws, size_t ws_size,
                              hipStream_t stream) {
    const float* in1 = (const float*)d_in[0];
    const float* in2 = (const float*)d_in[1];
    const float* gamma = (const float*)d_in[2];
    const float* beta = (const float*)d_in[3];
    const float* convw = (const float*)d_in[4];
    float* out = (float*)d_out;

    char* ws = (char*)d_ws;
    float* inv_norm = (float*)(ws + 0);                    //  28,160 B
    float* pool     = (float*)(ws + 28160);                //  28,160 B
    float* feats    = (float*)(ws + 56320);                //   3,600 B
    float* siml     = (float*)(ws + 59920);                //   1,200 B
    float* part_p   = (float*)(ws + 61120);                //   8,400 B
    size_t o = 69520;
    uint4* Pq_hi = (uint4*)(ws + o); o += 3440640;
    uint4* Pq_lo = (uint4*)(ws + o); o += 3440640;
    uint4* Ps_hi = (uint4*)(ws + o); o += 2826240;
    uint4* Ps_lo = (uint4*)(ws + o); o += 2826240;
    uint4* Al_hi = (uint4*)(ws + o); o += 2867200;
    uint4* Al_lo = (uint4*)(ws + o); o += 2867200;
    uint4* Bl_hi = (uint4*)(ws + o); o += 3440640;
    uint4* Bl_lo = (uint4*)(ws + o); o += 3440640;   // total ~25.2 MB

    k1_rownorm<<<dim3(1760), dim3(256), 0, stream>>>(in1, in2, inv_norm, pool);
    pack_q6<<<dim3(840), dim3(256), 0, stream>>>(in1, inv_norm, Pq_hi, Pq_lo);
    pack_s6<<<dim3(690), dim3(256), 0, stream>>>(in2, inv_norm, Ps_hi, Ps_lo);
    pack_lA<<<dim3(700), dim3(256), 0, stream>>>(in2, inv_norm, Al_hi, Al_lo);
    pack_lB<<<dim3(840), dim3(256), 0, stream>>>(in1, inv_norm, Bl_hi, Bl_lo);
    k4_cos<<<dim3(2), dim3(256), 0, stream>>>(pool, feats);
    k5_mfma<<<dim3(300), dim3(256), 0, stream>>>((const bf16x8*)Bl_hi, (const bf16x8*)Bl_lo,
                                                 (const bf16x8*)Al_hi, (const bf16x8*)Al_lo, siml);
    k6_mfma<<<dim3(2100), dim3(64), 0, stream>>>((const bf16x8*)Pq_hi, (const bf16x8*)Pq_lo,
                                                 (const bf16x8*)Ps_hi, (const bf16x8*)Ps_lo, part_p);
    k7_final<<<dim3(2), dim3(256), 0, stream>>>(feats, siml, part_p, gamma, beta, convw, out);
}

// Round 3
// 266.788 us; speedup vs baseline: 5.9968x; 1.2467x over previous
//
#include <hip/hip_runtime.h>
#include <math.h>

// B=2, WAY=5, SHOT=5, K=5, Q=30, DIM=64, HW=441
// MFMA plan (16x16x32 bf16, 3-term split bf16 = fp32-ish accuracy):
//  ip_p (pixel): per (e,w): C^T[k=sh*441+h (2205->2208)][col=(q,h) per-q 448], K=d(64)
//  ip_l (chan) : per (e,w): C^T[k=sh*64+d' (320)][col=(q,d) 1920], K=h(441->448)
// Transposed output => each lane's C column = one query row => per-lane top5 regs.

typedef __attribute__((ext_vector_type(8))) short bf16x8;
typedef __attribute__((ext_vector_type(4))) float f32x4;

#define MFMA16(a, b, c) __builtin_amdgcn_mfma_f32_16x16x32_bf16((a), (b), (c), 0, 0, 0)

__device__ __forceinline__ void split_bf16(float v, unsigned short& hi, unsigned short& lo) {
    unsigned int u = __float_as_uint(v);
    unsigned int r = u + 0x7FFFu + ((u >> 16) & 1u);
    hi = (unsigned short)(r >> 16);
    float hf = __uint_as_float(((unsigned int)hi) << 16);
    float l = v - hf;
    unsigned int u2 = __float_as_uint(l);
    unsigned int r2 = u2 + 0x7FFFu + ((u2 >> 16) & 1u);
    lo = (unsigned short)(r2 >> 16);
}

// sorted-desc top5 insert, v_med3_f32 form: 5 VALU ops.
// m[i] = med3(v, m[i], m[i-1]) (old m[i-1] >= m[i] invariant), m[0] = max.
__device__ __forceinline__ void ins5(float m[5], float v) {
    m[4] = __builtin_amdgcn_fmed3f(v, m[4], m[3]);
    m[3] = __builtin_amdgcn_fmed3f(v, m[3], m[2]);
    m[2] = __builtin_amdgcn_fmed3f(v, m[2], m[1]);
    m[1] = __builtin_amdgcn_fmed3f(v, m[1], m[0]);
    m[0] = fmaxf(m[0], v);
}

// ---------------- k1: row norms (1/||row||) + row means of raw input ----------------
__global__ __launch_bounds__(256) void k1_rownorm(const float* __restrict__ in1,
                                                  const float* __restrict__ in2,
                                                  float* __restrict__ inv_norm,
                                                  float* __restrict__ pool) {
    int wv = threadIdx.x >> 6;
    int lane = threadIdx.x & 63;
    int rid = blockIdx.x * 4 + wv;  // 0..7039
    const float* src = (rid < 3840) ? (in1 + (size_t)rid * 441)
                                    : (in2 + (size_t)(rid - 3840) * 441);
    float s = 0.f, ss = 0.f;
#pragma unroll
    for (int i = 0; i < 7; ++i) {
        int h = lane + i * 64;
        if (h < 441) { float v = src[h]; s += v; ss = fmaf(v, v, ss); }
    }
#pragma unroll
    for (int off = 32; off > 0; off >>= 1) {
        s += __shfl_xor(s, off, 64);
        ss += __shfl_xor(ss, off, 64);
    }
    if (lane == 0) {
        inv_norm[rid] = 1.0f / sqrtf(ss);
        pool[rid] = s * (1.0f / 441.0f);
    }
}

// ---------------- pack_all: 4 pack bodies + cosine logits, one launch ----------------
// Frag convention (16x16x32): row/col = lane&15 ; k = (lane>>4)*8 + j
__global__ __launch_bounds__(256, 4) void pack_all(const float* __restrict__ in1,
                                                   const float* __restrict__ in2,
                                                   const float* __restrict__ inv_norm,
                                                   const float* __restrict__ pool,
                                                   uint4* __restrict__ Pq_hi, uint4* __restrict__ Pq_lo,
                                                   uint4* __restrict__ Ps_hi, uint4* __restrict__ Ps_lo,
                                                   uint4* __restrict__ Al_hi, uint4* __restrict__ Al_lo,
                                                   uint4* __restrict__ Bl_hi, uint4* __restrict__ Bl_lo,
                                                   float* __restrict__ feats) {
    int bid = blockIdx.x;
    int tid = threadIdx.x;
    if (bid < 840) {
        // Pq: B-side of ip_p. col=h=cs*16+(lane&15), k=d
        int idx = bid * 256 + tid;
        int lane = idx & 63;
        int ks = (idx >> 6) & 1;
        int rest = idx >> 7;
        int gcs = rest % 840, e = rest / 840;
        int q = gcs / 28, cs = gcs % 28;
        int h = cs * 16 + (lane & 15);
        int d0 = ks * 32 + ((lane >> 4) << 3);
        int rowq = (e * 30 + q) * 64;
        unsigned short hs[8], ls[8];
#pragma unroll
        for (int j = 0; j < 8; ++j) {
            int d = d0 + j;
            float v = (h < 441) ? in1[(size_t)(rowq + d) * 441 + h] * inv_norm[rowq + d] : 0.f;
            split_bf16(v, hs[j], ls[j]);
        }
        uint4 H, L;
        H.x = hs[0] | (hs[1] << 16); H.y = hs[2] | (hs[3] << 16);
        H.z = hs[4] | (hs[5] << 16); H.w = hs[6] | (hs[7] << 16);
        L.x = ls[0] | (ls[1] << 16); L.y = ls[2] | (ls[3] << 16);
        L.z = ls[4] | (ls[5] << 16); L.w = ls[6] | (ls[7] << 16);
        Pq_hi[idx] = H; Pq_lo[idx] = L;
    } else if (bid < 1530) {
        // Ps: A-side of ip_p. row=kidx=kt*16+(lane&15), k=d
        int idx = (bid - 840) * 256 + tid;
        int lane = idx & 63;
        int ks = (idx >> 6) & 1;
        int rest = idx >> 7;
        int kt = rest % 138, ew = rest / 138;
        int kidx = kt * 16 + (lane & 15);
        bool valid = kidx < 2205;
        int kc = valid ? kidx : 0;
        int sh = kc / 441;
        int h = kc - sh * 441;
        int e = ew / 5, w = ew % 5;
        int srow = ((e * 25 + w * 5 + sh) * 64);
        int d0 = ks * 32 + ((lane >> 4) << 3);
        unsigned short hs[8], ls[8];
#pragma unroll
        for (int j = 0; j < 8; ++j) {
            int d = d0 + j;
            float v = valid ? in2[(size_t)(srow + d) * 441 + h] * inv_norm[3840 + srow + d] : 0.f;
            split_bf16(v, hs[j], ls[j]);
        }
        uint4 H, L;
        H.x = hs[0] | (hs[1] << 16); H.y = hs[2] | (hs[3] << 16);
        H.z = hs[4] | (hs[5] << 16); H.w = hs[6] | (hs[7] << 16);
        L.x = ls[0] | (ls[1] << 16); L.y = ls[2] | (ls[3] << 16);
        L.z = ls[4] | (ls[5] << 16); L.w = ls[6] | (ls[7] << 16);
        Ps_hi[idx] = H; Ps_lo[idx] = L;
    } else if (bid < 2230) {
        // Al: A-side of ip_l. row=sh*64+d'=rt*16+(lane&15), k=h
        int idx = (bid - 1530) * 256 + tid;
        int lane = idx & 63;
        int t2 = idx >> 6;
        int ks = t2 % 14;
        int t3 = t2 / 14;
        int rt = t3 % 20, ew = t3 / 20;
        int e = ew / 5, w = ew % 5;
        int row = rt * 16 + (lane & 15);  // < 320
        int sh = row >> 6, dp = row & 63;
        int srow = (e * 25 + w * 5 + sh) * 64 + dp;
        int h0 = ks * 32 + ((lane >> 4) << 3);
        const float* src = in2 + (size_t)srow * 441;
        float inv = inv_norm[3840 + srow];
        unsigned short hs[8], ls[8];
#pragma unroll
        for (int j = 0; j < 8; ++j) {
            int h = h0 + j;
            float v = (h < 441) ? src[h] * inv : 0.f;
            split_bf16(v, hs[j], ls[j]);
        }
        uint4 H, L;
        H.x = hs[0] | (hs[1] << 16); H.y = hs[2] | (hs[3] << 16);
        H.z = hs[4] | (hs[5] << 16); H.w = hs[6] | (hs[7] << 16);
        L.x = ls[0] | (ls[1] << 16); L.y = ls[2] | (ls[3] << 16);
        L.z = ls[4] | (ls[5] << 16); L.w = ls[6] | (ls[7] << 16);
        Al_hi[idx] = H; Al_lo[idx] = L;
    } else if (bid < 3070) {
        // Bl: B-side of ip_l. col=q*64+d=gct*16+(lane&15), k=h
        int idx = (bid - 2230) * 256 + tid;
        int lane = idx & 63;
        int t2 = idx >> 6;
        int ks = t2 % 14;
        int t3 = t2 / 14;
        int gct = t3 % 120, e = t3 / 120;
        int col = gct * 16 + (lane & 15);
        int q = col >> 6, d = col & 63;
        int qrow = (e * 30 + q) * 64 + d;
        int h0 = ks * 32 + ((lane >> 4) << 3);
        const float* src = in1 + (size_t)qrow * 441;
        float inv = inv_norm[qrow];
        unsigned short hs[8], ls[8];
#pragma unroll
        for (int j = 0; j < 8; ++j) {
            int h = h0 + j;
            float v = (h < 441) ? src[h] * inv : 0.f;
            split_bf16(v, hs[j], ls[j]);
        }
        uint4 H, L;
        H.x = hs[0] | (hs[1] << 16); H.y = hs[2] | (hs[3] << 16);
        H.z = hs[4] | (hs[5] << 16); H.w = hs[6] | (hs[7] << 16);
        L.x = ls[0] | (ls[1] << 16); L.y = ls[2] | (ls[3] << 16);
        L.z = ls[4] | (ls[5] << 16); L.w = ls[6] | (ls[7] << 16);
        Bl_hi[idx] = H; Bl_lo[idx] = L;
    } else {
        // cosine logits, e = bid - 3070
        int e = bid - 3070;
        __shared__ float qp[30 * 64], pr[5 * 64], qn[30], pn[5];
        int t = tid;
        for (int li = t; li < 1920; li += 256) qp[li] = pool[e * 30 * 64 + li];
        for (int li = t; li < 320; li += 256) {
            int w = li >> 6, d = li & 63;
            float sm = 0.f;
            for (int sh = 0; sh < 5; ++sh) sm += pool[(60 + e * 25 + w * 5 + sh) * 64 + d];
            pr[li] = sm * 0.2f;
        }
        __syncthreads();
        if (t < 30) {
            float ss = 0.f;
            for (int d = 0; d < 64; ++d) { float v = qp[t * 64 + d]; ss = fmaf(v, v, ss); }
            qn[t] = 1.0f / sqrtf(ss);
        }
        if (t >= 32 && t < 37) {
            int w = t - 32; float ss = 0.f;
            for (int d = 0; d < 64; ++d) { float v = pr[w * 64 + d]; ss = fmaf(v, v, ss); }
            pn[w] = 1.0f / sqrtf(ss);
        }
        __syncthreads();
        if (t < 150) {
            int q = t / 5, w = t % 5;
            float dp = 0.f;
            for (int d = 0; d < 64; ++d) dp = fmaf(qp[q * 64 + d], pr[w * 64 + d], dp);
            feats[(e * 30 + q) * 15 + w] = dp * qn[q] * pn[w];
        }
    }
}

// ---------------- k56: fused pixel (blocks 0..524, 4 indep waves each) +
//                        channel (blocks 525..824) similarity ----------------
__global__ __launch_bounds__(256, 2) void k56(const bf16x8* __restrict__ Pq_hi,
                                              const bf16x8* __restrict__ Pq_lo,
                                              const bf16x8* __restrict__ Ps_hi,
                                              const bf16x8* __restrict__ Ps_lo,
                                              const bf16x8* __restrict__ Bl_hi,
                                              const bf16x8* __restrict__ Bl_lo,
                                              const bf16x8* __restrict__ Al_hi,
                                              const bf16x8* __restrict__ Al_lo,
                                              float* __restrict__ part_p,
                                              float* __restrict__ siml) {
    __shared__ bf16x8 BH[14 * 4 * 64];     // 57344 B (k5 branch only)
    __shared__ float M[4][64][5];          // 5120 B
    int bid = blockIdx.x;
    int tid = threadIdx.x;
    if (bid < 525) {
        // ---- pixel similarity: wave-independent ----
        int gw = bid * 4 + (tid >> 6);     // 0..2099
        int lane = tid & 63;
        int gwave = gw % 210;
        int r = gw / 210;
        int w = r % 5, e = r / 5;
        int gcs0 = gwave * 4;
        int q = gwave / 7;
        int ew = e * 5 + w;

        bf16x8 Bh[4][2], Bl[4][2];
#pragma unroll
        for (int s = 0; s < 4; ++s)
#pragma unroll
            for (int ks = 0; ks < 2; ++ks) {
                int gi = ((e * 840 + gcs0 + s) * 2 + ks) * 64 + lane;
                Bh[s][ks] = Pq_hi[gi];
                Bl[s][ks] = Pq_lo[gi];
            }

        float m[4][5];
#pragma unroll
        for (int s = 0; s < 4; ++s)
#pragma unroll
            for (int i = 0; i < 5; ++i) m[s][i] = -1e30f;

        int rowbase = (lane >> 4) * 4;

        int abase = (ew * 138) * 2 * 64 + lane;
        bf16x8 Ah0 = Ps_hi[abase], Ah1 = Ps_hi[abase + 64];
        bf16x8 Al0 = Ps_lo[abase], Al1 = Ps_lo[abase + 64];

        for (int kt = 0; kt < 138; ++kt) {
            int ktn = (kt < 137) ? kt + 1 : 137;
            int nb = abase + ktn * 128;
            bf16x8 nAh0 = Ps_hi[nb], nAh1 = Ps_hi[nb + 64];
            bf16x8 nAl0 = Ps_lo[nb], nAl1 = Ps_lo[nb + 64];
#pragma unroll
            for (int s = 0; s < 4; ++s) {
                f32x4 c = {0.f, 0.f, 0.f, 0.f};
                c = MFMA16(Ah0, Bh[s][0], c);
                c = MFMA16(Ah1, Bh[s][1], c);
                c = MFMA16(Ah0, Bl[s][0], c);
                c = MFMA16(Ah1, Bl[s][1], c);
                c = MFMA16(Al0, Bh[s][0], c);
                c = MFMA16(Al1, Bh[s][1], c);
                if (kt == 137) {
#pragma unroll
                    for (int reg = 0; reg < 4; ++reg) {
                        float v = (rowbase + reg < 13) ? c[reg] : -1e30f;
                        ins5(m[s], v);
                    }
                } else {
#pragma unroll
                    for (int reg = 0; reg < 4; ++reg) ins5(m[s], c[reg]);
                }
            }
            Ah0 = nAh0; Ah1 = nAh1; Al0 = nAl0; Al1 = nAl1;
        }

        // merge per-set top5 across the 4 lane-groups (row quads)
#pragma unroll
        for (int mask = 16; mask <= 32; mask <<= 1) {
            float ov[4][5];
#pragma unroll
            for (int s = 0; s < 4; ++s)
#pragma unroll
                for (int i = 0; i < 5; ++i) ov[s][i] = __shfl_xor(m[s][i], mask, 64);
#pragma unroll
            for (int s = 0; s < 4; ++s)
#pragma unroll
                for (int i = 0; i < 5; ++i) ins5(m[s], ov[s][i]);
        }

        float tot = 0.f;
#pragma unroll
        for (int s = 0; s < 4; ++s) {
            float s5 = m[s][0] + m[s][1] + m[s][2] + m[s][3] + m[s][4];
            int h = ((gcs0 + s) % 28) * 16 + (lane & 15);
            s5 = (h < 441) ? s5 : 0.f;
#pragma unroll
            for (int mask = 1; mask <= 8; mask <<= 1) s5 += __shfl_xor(s5, mask, 64);
            tot += s5;
        }
        if (lane == 0) {
            int slot = gwave - 7 * q;     // 0..6
            part_p[((e * 30 + q) * 5 + w) * 7 + slot] = tot;
        }
    } else {
        // ---- channel similarity ----
        int b = bid - 525;                 // 0..299
        int w = b % 5;
        int r = b / 5;
        int q = r % 30, e = r / 30;
        int t = tid;
        int lane = t & 63, wid = t >> 6;
        int ew = e * 5 + w;

        for (int i = t; i < 3584; i += 256) {
            int ks = i >> 8;
            int rem = i & 255;
            int set = rem >> 6, ln = rem & 63;
            BH[i] = Bl_hi[((e * 120 + q * 4 + set) * 14 + ks) * 64 + ln];
        }
        __syncthreads();

        float m[4][5];
#pragma unroll
        for (int s = 0; s < 4; ++s)
#pragma unroll
            for (int i = 0; i < 5; ++i) m[s][i] = -1e30f;

        for (int rr = 0; rr < 5; ++rr) {
            int rt = wid * 5 + rr;
            f32x4 c[4];
#pragma unroll
            for (int s = 0; s < 4; ++s) c[s] = (f32x4){0.f, 0.f, 0.f, 0.f};
            for (int ks = 0; ks < 14; ++ks) {
                int ga = ((ew * 20 + rt) * 14 + ks) * 64 + lane;
                bf16x8 Ah = Al_hi[ga], Alo = Al_lo[ga];
#pragma unroll
                for (int s = 0; s < 4; ++s) {
                    bf16x8 bh = BH[(ks * 4 + s) * 64 + lane];
                    bf16x8 bl = Bl_lo[((e * 120 + q * 4 + s) * 14 + ks) * 64 + lane];
                    c[s] = MFMA16(Ah, bh, c[s]);
                    c[s] = MFMA16(Ah, bl, c[s]);
                    c[s] = MFMA16(Alo, bh, c[s]);
                }
            }
#pragma unroll
            for (int s = 0; s < 4; ++s)
#pragma unroll
                for (int reg = 0; reg < 4; ++reg) ins5(m[s], c[s][reg]);
        }

#pragma unroll
        for (int mask = 16; mask <= 32; mask <<= 1) {
            float ov[4][5];
#pragma unroll
            for (int s = 0; s < 4; ++s)
#pragma unroll
                for (int i = 0; i < 5; ++i) ov[s][i] = __shfl_xor(m[s][i], mask, 64);
#pragma unroll
            for (int s = 0; s < 4; ++s)
#pragma unroll
                for (int i = 0; i < 5; ++i) ins5(m[s], ov[s][i]);
        }

        if (lane < 16) {
#pragma unroll
            for (int s = 0; s < 4; ++s)
#pragma unroll
                for (int i = 0; i < 5; ++i) M[wid][s * 16 + lane][i] = m[s][i];
        }
        __syncthreads();

        if (t < 64) {
            float lst[5];
#pragma unroll
            for (int i = 0; i < 5; ++i) lst[i] = M[0][t][i];
#pragma unroll
            for (int wv = 1; wv < 4; ++wv)
#pragma unroll
                for (int i = 0; i < 5; ++i) ins5(lst, M[wv][t][i]);
            float s5 = lst[0] + lst[1] + lst[2] + lst[3] + lst[4];
#pragma unroll
            for (int mask = 1; mask <= 32; mask <<= 1) s5 += __shfl_xor(s5, mask, 64);
            if (t == 0) siml[(e * 30 + q) * 5 + w] = s5;
        }
    }
}

// ---------------- k7: BN (episode stats) + dilated conv ----------------
__global__ __launch_bounds__(256) void k7_final(const float* __restrict__ feats,
                                                const float* __restrict__ siml,
                                                const float* __restrict__ part_p,
                                                const float* __restrict__ gamma,
                                                const float* __restrict__ beta,
                                                const float* __restrict__ convw,
                                                float* __restrict__ out) {
    int e = blockIdx.x;
    __shared__ float f[30 * 15], mu[15], inv[15];
    int t = threadIdx.x;
    if (t < 150) {
        int q = t / 5, w = t % 5;
        int pb = ((e * 30 + q) * 5 + w) * 7;
        float sp = 0.f;
#pragma unroll
        for (int s = 0; s < 7; ++s) sp += part_p[pb + s];
        f[q * 15 + w] = feats[(e * 30 + q) * 15 + w];
        f[q * 15 + 5 + w] = siml[(e * 30 + q) * 5 + w];
        f[q * 15 + 10 + w] = sp;
    }
    __syncthreads();
    if (t < 15) {
        float s1 = 0.f;
        for (int q = 0; q < 30; ++q) s1 += f[q * 15 + t];
        float mn = s1 * (1.0f / 30.0f);
        float s2 = 0.f;
        for (int q = 0; q < 30; ++q) { float d = f[q * 15 + t] - mn; s2 = fmaf(d, d, s2); }
        mu[t] = mn;
        inv[t] = 1.0f / sqrtf(s2 * (1.0f / 30.0f) + 1e-5f);
    }
    __syncthreads();
    if (t < 150) {
        int q = t / 5, j = t % 5;
        float w0 = convw[0], w1 = convw[1], w2 = convw[2];
        float b0 = (f[q * 15 + j]      - mu[j])      * inv[j]      * gamma[j]      + beta[j];
        float b1 = (f[q * 15 + 5 + j]  - mu[5 + j])  * inv[5 + j]  * gamma[5 + j]  + beta[5 + j];
        float b2 = (f[q * 15 + 10 + j] - mu[10 + j]) * inv[10 + j] * gamma[10 + j] + beta[10 + j];
        out[e * 150 + q * 5 + j] = w0 * b0 + w1 * b1 + w2 * b2;
    }
}

extern "C" void kernel_launch(void* const* d_in, const int* in_sizes, int n_in,
                              void* d_out, int out_size, void* d_ws, size_t ws_size,
                              hipStream_t stream) {
    const float* in1 = (const float*)d_in[0];
    const float* in2 = (const float*)d_in[1];
    const float* gamma = (const float*)d_in[2];
    const float* beta = (const float*)d_in[3];
    const float* convw = (const float*)d_in[4];
    float* out = (float*)d_out;

    char* ws = (char*)d_ws;
    float* inv_norm = (float*)(ws + 0);                    //  28,160 B
    float* pool     = (float*)(ws + 28160);                //  28,160 B
    float* feats    = (float*)(ws + 56320);                //   3,600 B
    float* siml     = (float*)(ws + 59920);                //   1,200 B
    float* part_p   = (float*)(ws + 61120);                //   8,400 B
    size_t o = 69520;
    uint4* Pq_hi = (uint4*)(ws + o); o += 3440640;
    uint4* Pq_lo = (uint4*)(ws + o); o += 3440640;
    uint4* Ps_hi = (uint4*)(ws + o); o += 2826240;
    uint4* Ps_lo = (uint4*)(ws + o); o += 2826240;
    uint4* Al_hi = (uint4*)(ws + o); o += 2867200;
    uint4* Al_lo = (uint4*)(ws + o); o += 2867200;
    uint4* Bl_hi = (uint4*)(ws + o); o += 3440640;
    uint4* Bl_lo = (uint4*)(ws + o); o += 3440640;   // total ~25.2 MB

    k1_rownorm<<<dim3(1760), dim3(256), 0, stream>>>(in1, in2, inv_norm, pool);
    pack_all<<<dim3(3072), dim3(256), 0, stream>>>(in1, in2, inv_norm, pool,
                                                   Pq_hi, Pq_lo, Ps_hi, Ps_lo,
                                                   Al_hi, Al_lo, Bl_hi, Bl_lo, feats);
    k56<<<dim3(825), dim3(256), 0, stream>>>((const bf16x8*)Pq_hi, (const bf16x8*)Pq_lo,
                                             (const bf16x8*)Ps_hi, (const bf16x8*)Ps_lo,
                                             (const bf16x8*)Bl_hi, (const bf16x8*)Bl_lo,
                                             (const bf16x8*)Al_hi, (const bf16x8*)Al_lo,
                                             part_p, siml);
    k7_final<<<dim3(2), dim3(256), 0, stream>>>(feats, siml, part_p, gamma, beta, convw, out);
}

// Round 4
// 182.955 us; speedup vs baseline: 8.7446x; 1.4582x over previous
//
#include <hip/hip_runtime.h>
#include <math.h>

// B=2, WAY=5, SHOT=5, K=5, Q=30, DIM=64, HW=441
// MFMA plan (16x16x32 bf16, 3-term split bf16):
//  ip_p: per (e,w): C^T[k=sh*441+h (2208)][cols=(q,h) 448/q], K=d(64)
//  ip_l: per (e,w): C^T[k=sh*64+d' (320)][cols=(q,d) 1920], K=h(448)
// k56: XCD-grouped grid; pixel blocks = 4 waves sharing one (e,w) A-stream
// staged through an 8KB LDS double-buffer; channel = 2-pass rr split, no LDS
// staging. Both branches sized to fit the 128-VGPR occupancy step (no spill).

typedef __attribute__((ext_vector_type(8))) short bf16x8;
typedef __attribute__((ext_vector_type(4))) float f32x4;

#define MFMA16(a, b, c) __builtin_amdgcn_mfma_f32_16x16x32_bf16((a), (b), (c), 0, 0, 0)

__device__ __forceinline__ void split_bf16(float v, unsigned short& hi, unsigned short& lo) {
    unsigned int u = __float_as_uint(v);
    unsigned int r = u + 0x7FFFu + ((u >> 16) & 1u);
    hi = (unsigned short)(r >> 16);
    float hf = __uint_as_float(((unsigned int)hi) << 16);
    float l = v - hf;
    unsigned int u2 = __float_as_uint(l);
    unsigned int r2 = u2 + 0x7FFFu + ((u2 >> 16) & 1u);
    lo = (unsigned short)(r2 >> 16);
}

// sorted-desc top5 insert via v_med3_f32: 5 VALU ops.
__device__ __forceinline__ void ins5(float m[5], float v) {
    m[4] = __builtin_amdgcn_fmed3f(v, m[4], m[3]);
    m[3] = __builtin_amdgcn_fmed3f(v, m[3], m[2]);
    m[2] = __builtin_amdgcn_fmed3f(v, m[2], m[1]);
    m[1] = __builtin_amdgcn_fmed3f(v, m[1], m[0]);
    m[0] = fmaxf(m[0], v);
}

// ---------------- k1: row norms + row means ----------------
__global__ __launch_bounds__(256) void k1_rownorm(const float* __restrict__ in1,
                                                  const float* __restrict__ in2,
                                                  float* __restrict__ inv_norm,
                                                  float* __restrict__ pool) {
    int wv = threadIdx.x >> 6;
    int lane = threadIdx.x & 63;
    int rid = blockIdx.x * 4 + wv;  // 0..7039
    const float* src = (rid < 3840) ? (in1 + (size_t)rid * 441)
                                    : (in2 + (size_t)(rid - 3840) * 441);
    float s = 0.f, ss = 0.f;
#pragma unroll
    for (int i = 0; i < 7; ++i) {
        int h = lane + i * 64;
        if (h < 441) { float v = src[h]; s += v; ss = fmaf(v, v, ss); }
    }
#pragma unroll
    for (int off = 32; off > 0; off >>= 1) {
        s += __shfl_xor(s, off, 64);
        ss += __shfl_xor(ss, off, 64);
    }
    if (lane == 0) {
        inv_norm[rid] = 1.0f / sqrtf(ss);
        pool[rid] = s * (1.0f / 441.0f);
    }
}

// ---------------- pack_all: 4 pack bodies + cosine logits ----------------
// Frag convention (16x16x32): row/col = lane&15 ; k = (lane>>4)*8 + j
__global__ __launch_bounds__(256, 4) void pack_all(const float* __restrict__ in1,
                                                   const float* __restrict__ in2,
                                                   const float* __restrict__ inv_norm,
                                                   const float* __restrict__ pool,
                                                   uint4* __restrict__ Pq_hi, uint4* __restrict__ Pq_lo,
                                                   uint4* __restrict__ Ps_hi, uint4* __restrict__ Ps_lo,
                                                   uint4* __restrict__ Al_hi, uint4* __restrict__ Al_lo,
                                                   uint4* __restrict__ Bl_hi, uint4* __restrict__ Bl_lo,
                                                   float* __restrict__ feats) {
    int bid = blockIdx.x;
    int tid = threadIdx.x;
    if (bid < 840) {
        int idx = bid * 256 + tid;
        int lane = idx & 63;
        int ks = (idx >> 6) & 1;
        int rest = idx >> 7;
        int gcs = rest % 840, e = rest / 840;
        int q = gcs / 28, cs = gcs % 28;
        int h = cs * 16 + (lane & 15);
        int d0 = ks * 32 + ((lane >> 4) << 3);
        int rowq = (e * 30 + q) * 64;
        unsigned short hs[8], ls[8];
#pragma unroll
        for (int j = 0; j < 8; ++j) {
            int d = d0 + j;
            float v = (h < 441) ? in1[(size_t)(rowq + d) * 441 + h] * inv_norm[rowq + d] : 0.f;
            split_bf16(v, hs[j], ls[j]);
        }
        uint4 H, L;
        H.x = hs[0] | (hs[1] << 16); H.y = hs[2] | (hs[3] << 16);
        H.z = hs[4] | (hs[5] << 16); H.w = hs[6] | (hs[7] << 16);
        L.x = ls[0] | (ls[1] << 16); L.y = ls[2] | (ls[3] << 16);
        L.z = ls[4] | (ls[5] << 16); L.w = ls[6] | (ls[7] << 16);
        Pq_hi[idx] = H; Pq_lo[idx] = L;
    } else if (bid < 1530) {
        int idx = (bid - 840) * 256 + tid;
        int lane = idx & 63;
        int ks = (idx >> 6) & 1;
        int rest = idx >> 7;
        int kt = rest % 138, ew = rest / 138;
        int kidx = kt * 16 + (lane & 15);
        bool valid = kidx < 2205;
        int kc = valid ? kidx : 0;
        int sh = kc / 441;
        int h = kc - sh * 441;
        int e = ew / 5, w = ew % 5;
        int srow = ((e * 25 + w * 5 + sh) * 64);
        int d0 = ks * 32 + ((lane >> 4) << 3);
        unsigned short hs[8], ls[8];
#pragma unroll
        for (int j = 0; j < 8; ++j) {
            int d = d0 + j;
            float v = valid ? in2[(size_t)(srow + d) * 441 + h] * inv_norm[3840 + srow + d] : 0.f;
            split_bf16(v, hs[j], ls[j]);
        }
        uint4 H, L;
        H.x = hs[0] | (hs[1] << 16); H.y = hs[2] | (hs[3] << 16);
        H.z = hs[4] | (hs[5] << 16); H.w = hs[6] | (hs[7] << 16);
        L.x = ls[0] | (ls[1] << 16); L.y = ls[2] | (ls[3] << 16);
        L.z = ls[4] | (ls[5] << 16); L.w = ls[6] | (ls[7] << 16);
        Ps_hi[idx] = H; Ps_lo[idx] = L;
    } else if (bid < 2230) {
        int idx = (bid - 1530) * 256 + tid;
        int lane = idx & 63;
        int t2 = idx >> 6;
        int ks = t2 % 14;
        int t3 = t2 / 14;
        int rt = t3 % 20, ew = t3 / 20;
        int e = ew / 5, w = ew % 5;
        int row = rt * 16 + (lane & 15);  // < 320
        int sh = row >> 6, dp = row & 63;
        int srow = (e * 25 + w * 5 + sh) * 64 + dp;
        int h0 = ks * 32 + ((lane >> 4) << 3);
        const float* src = in2 + (size_t)srow * 441;
        float inv = inv_norm[3840 + srow];
        unsigned short hs[8], ls[8];
#pragma unroll
        for (int j = 0; j < 8; ++j) {
            int h = h0 + j;
            float v = (h < 441) ? src[h] * inv : 0.f;
            split_bf16(v, hs[j], ls[j]);
        }
        uint4 H, L;
        H.x = hs[0] | (hs[1] << 16); H.y = hs[2] | (hs[3] << 16);
        H.z = hs[4] | (hs[5] << 16); H.w = hs[6] | (hs[7] << 16);
        L.x = ls[0] | (ls[1] << 16); L.y = ls[2] | (ls[3] << 16);
        L.z = ls[4] | (ls[5] << 16); L.w = ls[6] | (ls[7] << 16);
        Al_hi[idx] = H; Al_lo[idx] = L;
    } else if (bid < 3070) {
        int idx = (bid - 2230) * 256 + tid;
        int lane = idx & 63;
        int t2 = idx >> 6;
        int ks = t2 % 14;
        int t3 = t2 / 14;
        int gct = t3 % 120, e = t3 / 120;
        int col = gct * 16 + (lane & 15);
        int q = col >> 6, d = col & 63;
        int qrow = (e * 30 + q) * 64 + d;
        int h0 = ks * 32 + ((lane >> 4) << 3);
        const float* src = in1 + (size_t)qrow * 441;
        float inv = inv_norm[qrow];
        unsigned short hs[8], ls[8];
#pragma unroll
        for (int j = 0; j < 8; ++j) {
            int h = h0 + j;
            float v = (h < 441) ? src[h] * inv : 0.f;
            split_bf16(v, hs[j], ls[j]);
        }
        uint4 H, L;
        H.x = hs[0] | (hs[1] << 16); H.y = hs[2] | (hs[3] << 16);
        H.z = hs[4] | (hs[5] << 16); H.w = hs[6] | (hs[7] << 16);
        L.x = ls[0] | (ls[1] << 16); L.y = ls[2] | (ls[3] << 16);
        L.z = ls[4] | (ls[5] << 16); L.w = ls[6] | (ls[7] << 16);
        Bl_hi[idx] = H; Bl_lo[idx] = L;
    } else {
        int e = bid - 3070;
        __shared__ float qp[30 * 64], pr[5 * 64], qn[30], pn[5];
        int t = tid;
        for (int li = t; li < 1920; li += 256) qp[li] = pool[e * 30 * 64 + li];
        for (int li = t; li < 320; li += 256) {
            int w = li >> 6, d = li & 63;
            float sm = 0.f;
            for (int sh = 0; sh < 5; ++sh) sm += pool[(60 + e * 25 + w * 5 + sh) * 64 + d];
            pr[li] = sm * 0.2f;
        }
        __syncthreads();
        if (t < 30) {
            float ss = 0.f;
            for (int d = 0; d < 64; ++d) { float v = qp[t * 64 + d]; ss = fmaf(v, v, ss); }
            qn[t] = 1.0f / sqrtf(ss);
        }
        if (t >= 32 && t < 37) {
            int w = t - 32; float ss = 0.f;
            for (int d = 0; d < 64; ++d) { float v = pr[w * 64 + d]; ss = fmaf(v, v, ss); }
            pn[w] = 1.0f / sqrtf(ss);
        }
        __syncthreads();
        if (t < 150) {
            int q = t / 5, w = t % 5;
            float dp = 0.f;
            for (int d = 0; d < 64; ++d) dp = fmaf(qp[q * 64 + d], pr[w * 64 + d], dp);
            feats[(e * 30 + q) * 15 + w] = dp * qn[q] * pn[w];
        }
    }
}

// channel rr-pass: NRR row-tiles, accumulate full K then top5-insert into m.
template <int NRR>
__device__ __forceinline__ void chan_pass(int rr0, int ew, int e, int q, int wv, int lane,
                                          const bf16x8* __restrict__ Bl_hi,
                                          const bf16x8* __restrict__ Bl_lo,
                                          const bf16x8* __restrict__ Al_hi,
                                          const bf16x8* __restrict__ Al_lo,
                                          float m[4][5]) {
    f32x4 cc[NRR][4];
#pragma unroll
    for (int r = 0; r < NRR; ++r)
#pragma unroll
        for (int s = 0; s < 4; ++s) cc[r][s] = (f32x4){0.f, 0.f, 0.f, 0.f};
    for (int ks = 0; ks < 14; ++ks) {
        bf16x8 bh[4], bl[4];
#pragma unroll
        for (int s = 0; s < 4; ++s) {
            int gb = ((e * 120 + q * 4 + s) * 14 + ks) * 64 + lane;
            bh[s] = Bl_hi[gb];
            bl[s] = Bl_lo[gb];
        }
#pragma unroll
        for (int r = 0; r < NRR; ++r) {
            int ga = ((ew * 20 + wv * 5 + rr0 + r) * 14 + ks) * 64 + lane;
            bf16x8 ah = Al_hi[ga], al = Al_lo[ga];
#pragma unroll
            for (int s = 0; s < 4; ++s) {
                cc[r][s] = MFMA16(ah, bh[s], cc[r][s]);
                cc[r][s] = MFMA16(ah, bl[s], cc[r][s]);
                cc[r][s] = MFMA16(al, bh[s], cc[r][s]);
            }
        }
    }
#pragma unroll
    for (int r = 0; r < NRR; ++r)
#pragma unroll
        for (int s = 0; s < 4; ++s)
#pragma unroll
            for (int g = 0; g < 4; ++g) ins5(m[s], cc[r][s][g]);
}

// ---------------- k56: XCD-grouped pixel + channel ----------------
// grid = 8 XCD-columns x 105 slots. slot<67: pixel p=xcd*67+slot (530 active,
// p -> ew=p/53). slot>=67: channel c=xcd*38+(slot-67) (300 active, ew=c/30).
__global__ __launch_bounds__(256, 2) void k56(const bf16x8* __restrict__ Pq_hi,
                                              const bf16x8* __restrict__ Pq_lo,
                                              const uint4* __restrict__ Ps_hi,
                                              const uint4* __restrict__ Ps_lo,
                                              const bf16x8* __restrict__ Bl_hi,
                                              const bf16x8* __restrict__ Bl_lo,
                                              const bf16x8* __restrict__ Al_hi,
                                              const bf16x8* __restrict__ Al_lo,
                                              float* __restrict__ part_p,
                                              float* __restrict__ siml) {
    __shared__ uint4 Abuf[2][4][64];   // 8 KB pixel A double-buffer
    __shared__ float Mred[4][64][5];   // 5 KB channel cross-wave merge
    int bid = blockIdx.x;
    int tid = threadIdx.x;
    int xcd = bid & 7;
    int slot = bid >> 3;
    int wv = tid >> 6, lane = tid & 63;

    if (slot < 67) {
        // ---- pixel ----
        int p = xcd * 67 + slot;
        if (p >= 530) return;
        int ew = p / 53;
        int blk = p - ew * 53;
        int e = ew / 5, w = ew - (ew / 5) * 5;
        int gwave = blk * 4 + wv;
        bool act = gwave < 210;
        int gv = act ? gwave : 209;
        int q = gv / 7;
        int ct0 = gv * 4;          // col-tile base within e (stays inside q)

        bf16x8 Bh[4][2], Bl[4][2];
#pragma unroll
        for (int s = 0; s < 4; ++s)
#pragma unroll
            for (int ks = 0; ks < 2; ++ks) {
                int gi = ((e * 840 + ct0 + s) * 2 + ks) * 64 + lane;
                Bh[s][ks] = Pq_hi[gi];
                Bl[s][ks] = Pq_lo[gi];
            }

        float m[4][5];
#pragma unroll
        for (int s = 0; s < 4; ++s)
#pragma unroll
            for (int i = 0; i < 5; ++i) m[s][i] = -1e30f;

        int rowbase = (lane >> 4) * 4;

        // wave wv stages frag wv: {hi ks0, hi ks1, lo ks0, lo ks1}
        const uint4* src = ((wv & 2) ? Ps_lo : Ps_hi)
                           + (size_t)(ew * 138) * 128 + (wv & 1) * 64 + lane;
        Abuf[0][wv][lane] = src[0];
        __syncthreads();
        int cur = 0;
        for (int kt = 0; kt < 138; ++kt) {
            uint4 nxt;
            if (kt < 137) nxt = src[(size_t)(kt + 1) * 128];
            bf16x8 Ah0 = ((const bf16x8*)Abuf)[(cur * 4 + 0) * 64 + lane];
            bf16x8 Ah1 = ((const bf16x8*)Abuf)[(cur * 4 + 1) * 64 + lane];
            bf16x8 Al0 = ((const bf16x8*)Abuf)[(cur * 4 + 2) * 64 + lane];
            bf16x8 Al1 = ((const bf16x8*)Abuf)[(cur * 4 + 3) * 64 + lane];
            if (act) {
#pragma unroll
                for (int s = 0; s < 4; ++s) {
                    f32x4 c = {0.f, 0.f, 0.f, 0.f};
                    c = MFMA16(Ah0, Bh[s][0], c);
                    c = MFMA16(Ah1, Bh[s][1], c);
                    c = MFMA16(Ah0, Bl[s][0], c);
                    c = MFMA16(Ah1, Bl[s][1], c);
                    c = MFMA16(Al0, Bh[s][0], c);
                    c = MFMA16(Al1, Bh[s][1], c);
                    if (kt == 137) {
#pragma unroll
                        for (int g = 0; g < 4; ++g) {
                            float v = (rowbase + g < 13) ? c[g] : -1e30f;
                            ins5(m[s], v);
                        }
                    } else {
#pragma unroll
                        for (int g = 0; g < 4; ++g) ins5(m[s], c[g]);
                    }
                }
            }
            if (kt < 137) Abuf[cur ^ 1][wv][lane] = nxt;
            __syncthreads();
            cur ^= 1;
        }

#pragma unroll
        for (int mask = 16; mask <= 32; mask <<= 1) {
            float ov[4][5];
#pragma unroll
            for (int s = 0; s < 4; ++s)
#pragma unroll
                for (int i = 0; i < 5; ++i) ov[s][i] = __shfl_xor(m[s][i], mask, 64);
#pragma unroll
            for (int s = 0; s < 4; ++s)
#pragma unroll
                for (int i = 0; i < 5; ++i) ins5(m[s], ov[s][i]);
        }

        float tot = 0.f;
#pragma unroll
        for (int s = 0; s < 4; ++s) {
            float s5 = m[s][0] + m[s][1] + m[s][2] + m[s][3] + m[s][4];
            int h = ((ct0 + s) % 28) * 16 + (lane & 15);
            s5 = (h < 441) ? s5 : 0.f;
#pragma unroll
            for (int mask = 1; mask <= 8; mask <<= 1) s5 += __shfl_xor(s5, mask, 64);
            tot += s5;
        }
        if (act && lane == 0) {
            int sl = gv - q * 7;
            part_p[((e * 30 + q) * 5 + w) * 7 + sl] = tot;
        }
    } else {
        // ---- channel ----
        int c = xcd * 38 + (slot - 67);
        if (c >= 300) return;
        int ew = c / 30, q = c - ew * 30;
        int e = ew / 5, w = ew - (ew / 5) * 5;

        float m[4][5];
#pragma unroll
        for (int s = 0; s < 4; ++s)
#pragma unroll
            for (int i = 0; i < 5; ++i) m[s][i] = -1e30f;

        chan_pass<3>(0, ew, e, q, wv, lane, Bl_hi, Bl_lo, Al_hi, Al_lo, m);
        chan_pass<2>(3, ew, e, q, wv, lane, Bl_hi, Bl_lo, Al_hi, Al_lo, m);

#pragma unroll
        for (int mask = 16; mask <= 32; mask <<= 1) {
            float ov[4][5];
#pragma unroll
            for (int s = 0; s < 4; ++s)
#pragma unroll
                for (int i = 0; i < 5; ++i) ov[s][i] = __shfl_xor(m[s][i], mask, 64);
#pragma unroll
            for (int s = 0; s < 4; ++s)
#pragma unroll
                for (int i = 0; i < 5; ++i) ins5(m[s], ov[s][i]);
        }

        if (lane < 16) {
#pragma unroll
            for (int s = 0; s < 4; ++s)
#pragma unroll
                for (int i = 0; i < 5; ++i) Mred[wv][s * 16 + lane][i] = m[s][i];
        }
        __syncthreads();

        if (tid < 64) {
            float lst[5];
#pragma unroll
            for (int i = 0; i < 5; ++i) lst[i] = Mred[0][tid][i];
#pragma unroll
            for (int v2 = 1; v2 < 4; ++v2)
#pragma unroll
                for (int i = 0; i < 5; ++i) ins5(lst, Mred[v2][tid][i]);
            float s5 = lst[0] + lst[1] + lst[2] + lst[3] + lst[4];
#pragma unroll
            for (int mask = 1; mask <= 32; mask <<= 1) s5 += __shfl_xor(s5, mask, 64);
            if (tid == 0) siml[(e * 30 + q) * 5 + w] = s5;
        }
    }
}

// ---------------- k7: BN (episode stats) + dilated conv ----------------
__global__ __launch_bounds__(256) void k7_final(const float* __restrict__ feats,
                                                const float* __restrict__ siml,
                                                const float* __restrict__ part_p,
                                                const float* __restrict__ gamma,
                                                const float* __restrict__ beta,
                                                const float* __restrict__ convw,
                                                float* __restrict__ out) {
    int e = blockIdx.x;
    __shared__ float f[30 * 15], mu[15], inv[15];
    int t = threadIdx.x;
    if (t < 150) {
        int q = t / 5, w = t % 5;
        int pb = ((e * 30 + q) * 5 + w) * 7;
        float sp = 0.f;
#pragma unroll
        for (int s = 0; s < 7; ++s) sp += part_p[pb + s];
        f[q * 15 + w] = feats[(e * 30 + q) * 15 + w];
        f[q * 15 + 5 + w] = siml[(e * 30 + q) * 5 + w];
        f[q * 15 + 10 + w] = sp;
    }
    __syncthreads();
    if (t < 15) {
        float s1 = 0.f;
        for (int q = 0; q < 30; ++q) s1 += f[q * 15 + t];
        float mn = s1 * (1.0f / 30.0f);
        float s2 = 0.f;
        for (int q = 0; q < 30; ++q) { float d = f[q * 15 + t] - mn; s2 = fmaf(d, d, s2); }
        mu[t] = mn;
        inv[t] = 1.0f / sqrtf(s2 * (1.0f / 30.0f) + 1e-5f);
    }
    __syncthreads();
    if (t < 150) {
        int q = t / 5, j = t % 5;
        float w0 = convw[0], w1 = convw[1], w2 = convw[2];
        float b0 = (f[q * 15 + j]      - mu[j])      * inv[j]      * gamma[j]      + beta[j];
        float b1 = (f[q * 15 + 5 + j]  - mu[5 + j])  * inv[5 + j]  * gamma[5 + j]  + beta[5 + j];
        float b2 = (f[q * 15 + 10 + j] - mu[10 + j]) * inv[10 + j] * gamma[10 + j] + beta[10 + j];
        out[e * 150 + q * 5 + j] = w0 * b0 + w1 * b1 + w2 * b2;
    }
}

extern "C" void kernel_launch(void* const* d_in, const int* in_sizes, int n_in,
                              void* d_out, int out_size, void* d_ws, size_t ws_size,
                              hipStream_t stream) {
    const float* in1 = (const float*)d_in[0];
    const float* in2 = (const float*)d_in[1];
    const float* gamma = (const float*)d_in[2];
    const float* beta = (const float*)d_in[3];
    const float* convw = (const float*)d_in[4];
    float* out = (float*)d_out;

    char* ws = (char*)d_ws;
    float* inv_norm = (float*)(ws + 0);                    //  28,160 B
    float* pool     = (float*)(ws + 28160);                //  28,160 B
    float* feats    = (float*)(ws + 56320);                //   3,600 B
    float* siml     = (float*)(ws + 59920);                //   1,200 B
    float* part_p   = (float*)(ws + 61120);                //   8,400 B
    size_t o = 69520;
    uint4* Pq_hi = (uint4*)(ws + o); o += 3440640;
    uint4* Pq_lo = (uint4*)(ws + o); o += 3440640;
    uint4* Ps_hi = (uint4*)(ws + o); o += 2826240;
    uint4* Ps_lo = (uint4*)(ws + o); o += 2826240;
    uint4* Al_hi = (uint4*)(ws + o); o += 2867200;
    uint4* Al_lo = (uint4*)(ws + o); o += 2867200;
    uint4* Bl_hi = (uint4*)(ws + o); o += 3440640;
    uint4* Bl_lo = (uint4*)(ws + o); o += 3440640;   // total ~25.2 MB

    k1_rownorm<<<dim3(1760), dim3(256), 0, stream>>>(in1, in2, inv_norm, pool);
    pack_all<<<dim3(3072), dim3(256), 0, stream>>>(in1, in2, inv_norm, pool,
                                                   Pq_hi, Pq_lo, Ps_hi, Ps_lo,
                                                   Al_hi, Al_lo, Bl_hi, Bl_lo, feats);
    k56<<<dim3(840), dim3(256), 0, stream>>>((const bf16x8*)Pq_hi, (const bf16x8*)Pq_lo,
                                             Ps_hi, Ps_lo,
                                             (const bf16x8*)Bl_hi, (const bf16x8*)Bl_lo,
                                             (const bf16x8*)Al_hi, (const bf16x8*)Al_lo,
                                             part_p, siml);
    k7_final<<<dim3(2), dim3(256), 0, stream>>>(feats, siml, part_p, gamma, beta, convw, out);
}

// Round 5
// 131.807 us; speedup vs baseline: 12.1380x; 1.3881x over previous
//
#include <hip/hip_runtime.h>
#include <math.h>

// B=2, WAY=5, SHOT=5, K=5, Q=30, DIM=64, HW=441
// Single-bf16 MFMA (16x16x32). Error budget: bf16 input rounding -> per-dot
// ~7e-5, per-feature ~3.5e-3, output ~0.01-0.04 << 0.114 threshold.
//  ip_p: per (e,w): C^T[k=sh*441+h (2208)][cols=(q,h) 448/q], K=d(64)
//  ip_l: per (e,w): C^T[k=sh*64+d' (320)][cols=(q,d) 1920], K=h(448)
// k56 pixel: barrier-free waves, depth-2 register prefetch of A from L2.

typedef __attribute__((ext_vector_type(8))) short bf16x8;
typedef __attribute__((ext_vector_type(4))) float f32x4;

#define MFMA16(a, b, c) __builtin_amdgcn_mfma_f32_16x16x32_bf16((a), (b), (c), 0, 0, 0)

__device__ __forceinline__ unsigned short to_bf16(float v) {
    unsigned int u = __float_as_uint(v);
    unsigned int r = u + 0x7FFFu + ((u >> 16) & 1u);
    return (unsigned short)(r >> 16);
}

// sorted-desc top5 insert via v_med3_f32: 5 VALU ops, all reading OLD m -> ILP.
__device__ __forceinline__ void ins5(float m[5], float v) {
    m[4] = __builtin_amdgcn_fmed3f(v, m[4], m[3]);
    m[3] = __builtin_amdgcn_fmed3f(v, m[3], m[2]);
    m[2] = __builtin_amdgcn_fmed3f(v, m[2], m[1]);
    m[1] = __builtin_amdgcn_fmed3f(v, m[1], m[0]);
    m[0] = fmaxf(m[0], v);
}

// ---------------- k1: row norms + row means ----------------
__global__ __launch_bounds__(256) void k1_rownorm(const float* __restrict__ in1,
                                                  const float* __restrict__ in2,
                                                  float* __restrict__ inv_norm,
                                                  float* __restrict__ pool) {
    int wv = threadIdx.x >> 6;
    int lane = threadIdx.x & 63;
    int rid = blockIdx.x * 4 + wv;  // 0..7039
    const float* src = (rid < 3840) ? (in1 + (size_t)rid * 441)
                                    : (in2 + (size_t)(rid - 3840) * 441);
    float s = 0.f, ss = 0.f;
#pragma unroll
    for (int i = 0; i < 7; ++i) {
        int h = lane + i * 64;
        if (h < 441) { float v = src[h]; s += v; ss = fmaf(v, v, ss); }
    }
#pragma unroll
    for (int off = 32; off > 0; off >>= 1) {
        s += __shfl_xor(s, off, 64);
        ss += __shfl_xor(ss, off, 64);
    }
    if (lane == 0) {
        inv_norm[rid] = 1.0f / sqrtf(ss);
        pool[rid] = s * (1.0f / 441.0f);
    }
}

// ---------------- pack_all: 4 pack bodies + cosine logits ----------------
// Frag convention (16x16x32): row/col = lane&15 ; k = (lane>>4)*8 + j
__global__ __launch_bounds__(256, 4) void pack_all(const float* __restrict__ in1,
                                                   const float* __restrict__ in2,
                                                   const float* __restrict__ inv_norm,
                                                   const float* __restrict__ pool,
                                                   uint4* __restrict__ Pq,
                                                   uint4* __restrict__ Ps,
                                                   uint4* __restrict__ Al,
                                                   uint4* __restrict__ Bl,
                                                   float* __restrict__ feats) {
    int bid = blockIdx.x;
    int tid = threadIdx.x;
    unsigned short hs[8];
    if (bid < 840) {
        // Pq: B-side of ip_p. col=h=cs*16+(lane&15), k=d
        int idx = bid * 256 + tid;
        int lane = idx & 63;
        int ks = (idx >> 6) & 1;
        int rest = idx >> 7;
        int gcs = rest % 840, e = rest / 840;
        int q = gcs / 28, cs = gcs % 28;
        int h = cs * 16 + (lane & 15);
        int d0 = ks * 32 + ((lane >> 4) << 3);
        int rowq = (e * 30 + q) * 64;
#pragma unroll
        for (int j = 0; j < 8; ++j) {
            int d = d0 + j;
            float v = (h < 441) ? in1[(size_t)(rowq + d) * 441 + h] * inv_norm[rowq + d] : 0.f;
            hs[j] = to_bf16(v);
        }
        uint4 H;
        H.x = hs[0] | (hs[1] << 16); H.y = hs[2] | (hs[3] << 16);
        H.z = hs[4] | (hs[5] << 16); H.w = hs[6] | (hs[7] << 16);
        Pq[idx] = H;
    } else if (bid < 1530) {
        // Ps: A-side of ip_p. row=kidx=kt*16+(lane&15), k=d
        int idx = (bid - 840) * 256 + tid;
        int lane = idx & 63;
        int ks = (idx >> 6) & 1;
        int rest = idx >> 7;
        int kt = rest % 138, ew = rest / 138;
        int kidx = kt * 16 + (lane & 15);
        bool valid = kidx < 2205;
        int kc = valid ? kidx : 0;
        int sh = kc / 441;
        int h = kc - sh * 441;
        int e = ew / 5, w = ew % 5;
        int srow = ((e * 25 + w * 5 + sh) * 64);
        int d0 = ks * 32 + ((lane >> 4) << 3);
#pragma unroll
        for (int j = 0; j < 8; ++j) {
            int d = d0 + j;
            float v = valid ? in2[(size_t)(srow + d) * 441 + h] * inv_norm[3840 + srow + d] : 0.f;
            hs[j] = to_bf16(v);
        }
        uint4 H;
        H.x = hs[0] | (hs[1] << 16); H.y = hs[2] | (hs[3] << 16);
        H.z = hs[4] | (hs[5] << 16); H.w = hs[6] | (hs[7] << 16);
        Ps[idx] = H;
    } else if (bid < 2230) {
        // Al: A-side of ip_l. row=rt*16+(lane&15) (=sh*64+d'), k=h
        int idx = (bid - 1530) * 256 + tid;
        int lane = idx & 63;
        int t2 = idx >> 6;
        int ks = t2 % 14;
        int t3 = t2 / 14;
        int rt = t3 % 20, ew = t3 / 20;
        int e = ew / 5, w = ew % 5;
        int row = rt * 16 + (lane & 15);  // < 320
        int sh = row >> 6, dp = row & 63;
        int srow = (e * 25 + w * 5 + sh) * 64 + dp;
        int h0 = ks * 32 + ((lane >> 4) << 3);
        const float* src = in2 + (size_t)srow * 441;
        float inv = inv_norm[3840 + srow];
#pragma unroll
        for (int j = 0; j < 8; ++j) {
            int h = h0 + j;
            float v = (h < 441) ? src[h] * inv : 0.f;
            hs[j] = to_bf16(v);
        }
        uint4 H;
        H.x = hs[0] | (hs[1] << 16); H.y = hs[2] | (hs[3] << 16);
        H.z = hs[4] | (hs[5] << 16); H.w = hs[6] | (hs[7] << 16);
        Al[idx] = H;
    } else if (bid < 3070) {
        // Bl: B-side of ip_l. col=gct*16+(lane&15) (=q*64+d), k=h
        int idx = (bid - 2230) * 256 + tid;
        int lane = idx & 63;
        int t2 = idx >> 6;
        int ks = t2 % 14;
        int t3 = t2 / 14;
        int gct = t3 % 120, e = t3 / 120;
        int col = gct * 16 + (lane & 15);
        int q = col >> 6, d = col & 63;
        int qrow = (e * 30 + q) * 64 + d;
        int h0 = ks * 32 + ((lane >> 4) << 3);
        const float* src = in1 + (size_t)qrow * 441;
        float inv = inv_norm[qrow];
#pragma unroll
        for (int j = 0; j < 8; ++j) {
            int h = h0 + j;
            float v = (h < 441) ? src[h] * inv : 0.f;
            hs[j] = to_bf16(v);
        }
        uint4 H;
        H.x = hs[0] | (hs[1] << 16); H.y = hs[2] | (hs[3] << 16);
        H.z = hs[4] | (hs[5] << 16); H.w = hs[6] | (hs[7] << 16);
        Bl[idx] = H;
    } else {
        // cosine logits
        int e = bid - 3070;
        __shared__ float qp[30 * 64], pr[5 * 64], qn[30], pn[5];
        int t = tid;
        for (int li = t; li < 1920; li += 256) qp[li] = pool[e * 30 * 64 + li];
        for (int li = t; li < 320; li += 256) {
            int w = li >> 6, d = li & 63;
            float sm = 0.f;
            for (int sh = 0; sh < 5; ++sh) sm += pool[(60 + e * 25 + w * 5 + sh) * 64 + d];
            pr[li] = sm * 0.2f;
        }
        __syncthreads();
        if (t < 30) {
            float ss = 0.f;
            for (int d = 0; d < 64; ++d) { float v = qp[t * 64 + d]; ss = fmaf(v, v, ss); }
            qn[t] = 1.0f / sqrtf(ss);
        }
        if (t >= 32 && t < 37) {
            int w = t - 32; float ss = 0.f;
            for (int d = 0; d < 64; ++d) { float v = pr[w * 64 + d]; ss = fmaf(v, v, ss); }
            pn[w] = 1.0f / sqrtf(ss);
        }
        __syncthreads();
        if (t < 150) {
            int q = t / 5, w = t % 5;
            float dp = 0.f;
            for (int d = 0; d < 64; ++d) dp = fmaf(qp[q * 64 + d], pr[w * 64 + d], dp);
            feats[(e * 30 + q) * 15 + w] = dp * qn[q] * pn[w];
        }
    }
}

// channel rr-pass: NRR row-tiles, full-K accumulate, then top5-insert.
template <int NRR>
__device__ __forceinline__ void chan_pass(int rr0, int ew, int e, int q, int wv, int lane,
                                          const bf16x8* __restrict__ Bl,
                                          const bf16x8* __restrict__ Al,
                                          float m[4][5]) {
    f32x4 cc[NRR][4];
#pragma unroll
    for (int r = 0; r < NRR; ++r)
#pragma unroll
        for (int s = 0; s < 4; ++s) cc[r][s] = (f32x4){0.f, 0.f, 0.f, 0.f};
    for (int ks = 0; ks < 14; ++ks) {
        bf16x8 bh[4];
#pragma unroll
        for (int s = 0; s < 4; ++s)
            bh[s] = Bl[((e * 120 + q * 4 + s) * 14 + ks) * 64 + lane];
#pragma unroll
        for (int r = 0; r < NRR; ++r) {
            bf16x8 ah = Al[((ew * 20 + wv * 5 + rr0 + r) * 14 + ks) * 64 + lane];
#pragma unroll
            for (int s = 0; s < 4; ++s) cc[r][s] = MFMA16(ah, bh[s], cc[r][s]);
        }
    }
#pragma unroll
    for (int r = 0; r < NRR; ++r)
#pragma unroll
        for (int s = 0; s < 4; ++s)
#pragma unroll
            for (int g = 0; g < 4; ++g) ins5(m[s], cc[r][s][g]);
}

// ---------------- k56: XCD-grouped pixel + channel ----------------
// grid = 8 XCDs x 105 slots. slot<67: pixel p=xcd*67+slot (530 active).
// slot>=67: channel c=xcd*38+(slot-67) (300 active).
__global__ __launch_bounds__(256, 4) void k56(const bf16x8* __restrict__ Pq,
                                              const bf16x8* __restrict__ Ps,
                                              const bf16x8* __restrict__ Bl,
                                              const bf16x8* __restrict__ Al,
                                              float* __restrict__ part_p,
                                              float* __restrict__ siml) {
    __shared__ float Mred[4][64][5];   // channel cross-wave merge only
    int bid = blockIdx.x;
    int tid = threadIdx.x;
    int xcd = bid & 7;
    int slot = bid >> 3;
    int wv = tid >> 6, lane = tid & 63;

    if (slot < 67) {
        // ---- pixel: barrier-free, per-wave depth-2 prefetch ----
        int p = xcd * 67 + slot;
        if (p >= 530) return;
        int ew = p / 53;
        int blk = p - ew * 53;
        int e = ew / 5, w = ew - (ew / 5) * 5;
        int gwave = blk * 4 + wv;
        if (gwave >= 210) return;
        int q = gwave / 7;
        int ct0 = gwave * 4;       // col-tile base within e (stays inside q)

        bf16x8 Bh[4][2];
#pragma unroll
        for (int s = 0; s < 4; ++s)
#pragma unroll
            for (int ks = 0; ks < 2; ++ks)
                Bh[s][ks] = Pq[((e * 840 + ct0 + s) * 2 + ks) * 64 + lane];

        float m[4][5];
#pragma unroll
        for (int s = 0; s < 4; ++s)
#pragma unroll
            for (int i = 0; i < 5; ++i) m[s][i] = -1e30f;

        int rowbase = (lane >> 4) * 4;

        const bf16x8* As = Ps + (size_t)(ew * 138) * 128 + lane;
        bf16x8 a0 = As[0], a1 = As[64];
        bf16x8 b0 = As[128], b1 = As[192];

        for (int kt = 0; kt < 138; ++kt) {
            bf16x8 n0, n1;
            if (kt < 136) {
                n0 = As[(size_t)(kt + 2) * 128];
                n1 = As[(size_t)(kt + 2) * 128 + 64];
            }
#pragma unroll
            for (int s = 0; s < 4; ++s) {
                f32x4 c = {0.f, 0.f, 0.f, 0.f};
                c = MFMA16(a0, Bh[s][0], c);
                c = MFMA16(a1, Bh[s][1], c);
                if (kt == 137) {
#pragma unroll
                    for (int g = 0; g < 4; ++g) {
                        float v = (rowbase + g < 13) ? c[g] : -1e30f;
                        ins5(m[s], v);
                    }
                } else {
#pragma unroll
                    for (int g = 0; g < 4; ++g) ins5(m[s], c[g]);
                }
            }
            a0 = b0; a1 = b1; b0 = n0; b1 = n1;
        }

        // merge per-set top5 across the 4 row-quad lane groups
#pragma unroll
        for (int mask = 16; mask <= 32; mask <<= 1) {
            float ov[4][5];
#pragma unroll
            for (int s = 0; s < 4; ++s)
#pragma unroll
                for (int i = 0; i < 5; ++i) ov[s][i] = __shfl_xor(m[s][i], mask, 64);
#pragma unroll
            for (int s = 0; s < 4; ++s)
#pragma unroll
                for (int i = 0; i < 5; ++i) ins5(m[s], ov[s][i]);
        }

        float tot = 0.f;
#pragma unroll
        for (int s = 0; s < 4; ++s) {
            float s5 = m[s][0] + m[s][1] + m[s][2] + m[s][3] + m[s][4];
            int h = ((ct0 + s) % 28) * 16 + (lane & 15);
            s5 = (h < 441) ? s5 : 0.f;
#pragma unroll
            for (int mask = 1; mask <= 8; mask <<= 1) s5 += __shfl_xor(s5, mask, 64);
            tot += s5;
        }
        if (lane == 0) {
            int sl = gwave - q * 7;
            part_p[((e * 30 + q) * 5 + w) * 7 + sl] = tot;
        }
    } else {
        // ---- channel ----
        int c = xcd * 38 + (slot - 67);
        if (c >= 300) return;
        int ew = c / 30, q = c - ew * 30;
        int e = ew / 5, w = ew - (ew / 5) * 5;

        float m[4][5];
#pragma unroll
        for (int s = 0; s < 4; ++s)
#pragma unroll
            for (int i = 0; i < 5; ++i) m[s][i] = -1e30f;

        chan_pass<3>(0, ew, e, q, wv, lane, Bl, Al, m);
        chan_pass<2>(3, ew, e, q, wv, lane, Bl, Al, m);

#pragma unroll
        for (int mask = 16; mask <= 32; mask <<= 1) {
            float ov[4][5];
#pragma unroll
            for (int s = 0; s < 4; ++s)
#pragma unroll
                for (int i = 0; i < 5; ++i) ov[s][i] = __shfl_xor(m[s][i], mask, 64);
#pragma unroll
            for (int s = 0; s < 4; ++s)
#pragma unroll
                for (int i = 0; i < 5; ++i) ins5(m[s], ov[s][i]);
        }

        if (lane < 16) {
#pragma unroll
            for (int s = 0; s < 4; ++s)
#pragma unroll
                for (int i = 0; i < 5; ++i) Mred[wv][s * 16 + lane][i] = m[s][i];
        }
        __syncthreads();

        if (tid < 64) {
            float lst[5];
#pragma unroll
            for (int i = 0; i < 5; ++i) lst[i] = Mred[0][tid][i];
#pragma unroll
            for (int v2 = 1; v2 < 4; ++v2)
#pragma unroll
                for (int i = 0; i < 5; ++i) ins5(lst, Mred[v2][tid][i]);
            float s5 = lst[0] + lst[1] + lst[2] + lst[3] + lst[4];
#pragma unroll
            for (int mask = 1; mask <= 32; mask <<= 1) s5 += __shfl_xor(s5, mask, 64);
            if (tid == 0) siml[(e * 30 + q) * 5 + w] = s5;
        }
    }
}

// ---------------- k7: BN (episode stats) + dilated conv ----------------
__global__ __launch_bounds__(256) void k7_final(const float* __restrict__ feats,
                                                const float* __restrict__ siml,
                                                const float* __restrict__ part_p,
                                                const float* __restrict__ gamma,
                                                const float* __restrict__ beta,
                                                const float* __restrict__ convw,
                                                float* __restrict__ out) {
    int e = blockIdx.x;
    __shared__ float f[30 * 15], mu[15], inv[15];
    int t = threadIdx.x;
    if (t < 150) {
        int q = t / 5, w = t % 5;
        int pb = ((e * 30 + q) * 5 + w) * 7;
        float sp = 0.f;
#pragma unroll
        for (int s = 0; s < 7; ++s) sp += part_p[pb + s];
        f[q * 15 + w] = feats[(e * 30 + q) * 15 + w];
        f[q * 15 + 5 + w] = siml[(e * 30 + q) * 5 + w];
        f[q * 15 + 10 + w] = sp;
    }
    __syncthreads();
    if (t < 15) {
        float s1 = 0.f;
        for (int q = 0; q < 30; ++q) s1 += f[q * 15 + t];
        float mn = s1 * (1.0f / 30.0f);
        float s2 = 0.f;
        for (int q = 0; q < 30; ++q) { float d = f[q * 15 + t] - mn; s2 = fmaf(d, d, s2); }
        mu[t] = mn;
        inv[t] = 1.0f / sqrtf(s2 * (1.0f / 30.0f) + 1e-5f);
    }
    __syncthreads();
    if (t < 150) {
        int q = t / 5, j = t % 5;
        float w0 = convw[0], w1 = convw[1], w2 = convw[2];
        float b0 = (f[q * 15 + j]      - mu[j])      * inv[j]      * gamma[j]      + beta[j];
        float b1 = (f[q * 15 + 5 + j]  - mu[5 + j])  * inv[5 + j]  * gamma[5 + j]  + beta[5 + j];
        float b2 = (f[q * 15 + 10 + j] - mu[10 + j]) * inv[10 + j] * gamma[10 + j] + beta[10 + j];
        out[e * 150 + q * 5 + j] = w0 * b0 + w1 * b1 + w2 * b2;
    }
}

extern "C" void kernel_launch(void* const* d_in, const int* in_sizes, int n_in,
                              void* d_out, int out_size, void* d_ws, size_t ws_size,
                              hipStream_t stream) {
    const float* in1 = (const float*)d_in[0];
    const float* in2 = (const float*)d_in[1];
    const float* gamma = (const float*)d_in[2];
    const float* beta = (const float*)d_in[3];
    const float* convw = (const float*)d_in[4];
    float* out = (float*)d_out;

    char* ws = (char*)d_ws;
    float* inv_norm = (float*)(ws + 0);                    //  28,160 B
    float* pool     = (float*)(ws + 28160);                //  28,160 B
    float* feats    = (float*)(ws + 56320);                //   3,600 B
    float* siml     = (float*)(ws + 59920);                //   1,200 B
    float* part_p   = (float*)(ws + 61120);                //   8,400 B
    size_t o = 69520;
    uint4* Pq = (uint4*)(ws + o); o += 3440640;
    uint4* Ps = (uint4*)(ws + o); o += 2826240;
    uint4* Al = (uint4*)(ws + o); o += 2867200;
    uint4* Bl = (uint4*)(ws + o); o += 3440640;   // total ~12.7 MB

    k1_rownorm<<<dim3(1760), dim3(256), 0, stream>>>(in1, in2, inv_norm, pool);
    pack_all<<<dim3(3072), dim3(256), 0, stream>>>(in1, in2, inv_norm, pool,
                                                   Pq, Ps, Al, Bl, feats);
    k56<<<dim3(840), dim3(256), 0, stream>>>((const bf16x8*)Pq, (const bf16x8*)Ps,
                                             (const bf16x8*)Bl, (const bf16x8*)Al,
                                             part_p, siml);
    k7_final<<<dim3(2), dim3(256), 0, stream>>>(feats, siml, part_p, gamma, beta, convw, out);
}